// Round 14
// baseline (359.128 us; speedup 1.0000x reference)
//
#include <hip/hip_runtime.h>
#include <hip/hip_bf16.h>

typedef unsigned short u16;
typedef __bf16 bf16x8_t __attribute__((ext_vector_type(8)));
typedef float f32x4_t __attribute__((ext_vector_type(4)));
typedef unsigned int u32x4 __attribute__((ext_vector_type(4)));

struct alignas(8) us4 { u16 v[4]; };

__device__ __forceinline__ u16 f2bf(float f) {
  __hip_bfloat16 h = __float2bfloat16(f);
  u16 u; __builtin_memcpy(&u, &h, 2); return u;
}
__device__ __forceinline__ float bf2f(u16 u) {
  __hip_bfloat16 h; __builtin_memcpy(&h, &u, 2); return __bfloat162float(h);
}
__device__ __forceinline__ void gload16(const u16* g, u16* l) {
  __builtin_amdgcn_global_load_lds(
      (const __attribute__((address_space(1))) void*)g,
      (__attribute__((address_space(3))) void*)l, 16, 0, 0);
}
__device__ __forceinline__ void nts16(void* p, u32x4 v) {
  __builtin_nontemporal_store(v, (u32x4*)p);
}

#define BAR()  __builtin_amdgcn_s_barrier()
#define VMC(n) asm volatile("s_waitcnt vmcnt(%0)" :: "i"(n) : "memory")

// ============ projection kernel (zsel picks q/k/vo) ============
// launch A: grid 4096, zoff 0 -> zsel {0,1} (Q,K). launch B: grid 2048,
// zoff 2 -> zsel 2 (VO: V-proj with Wo pre-folded). 128x128, BK=32, 3-buf
// depth-2 counted-vmcnt (r9-proven), chunk-XOR swizzle both-sides.
// Weights pre-interleaved (col n -> h=(n>>4)&7, e=(n>>7)*16+(n&15)).
// zsel 0: softmax + qsP[b][s][n]. zsel 1: softmax + [b,h,e,s].
// zsel 2: bias(bvo) + [b,h,f,s]. All global stores non-temporal.
__global__ __launch_bounds__(256, 2)
void proj3_kernel(const u16* __restrict__ qb, const u16* __restrict__ kb,
                  const u16* __restrict__ vb, const u16* __restrict__ WqT,
                  const u16* __restrict__ WkT, const u16* __restrict__ WvoT,
                  const float* __restrict__ bq, const float* __restrict__ bk,
                  const float* __restrict__ bvo, u16* __restrict__ qs,
                  u16* __restrict__ ksT, u16* __restrict__ voT, int zoff)
{
  __shared__ __align__(16) u16 smem[24576];

  const int bid = blockIdx.x;
  const int chunk = gridDim.x >> 3;
  const int wg = (bid & 7) * chunk + (bid >> 3);
  const int zsel = zoff + (wg >> 11);
  const int rem = wg & 2047;
  const int by = rem >> 5;
  const int bx = rem & 31;

  const int tid = threadIdx.x;
  const int lane = tid & 63;
  const int wave = tid >> 6;
  const int wm = (wave >> 1) * 64;
  const int wn = (wave & 1) * 64;
  const int m0 = by * 128;

  const u16* Az = zsel == 0 ? qb : (zsel == 1 ? kb : vb);
  const u16* Bz = zsel == 0 ? WqT : (zsel == 1 ? WkT : WvoT);
  const float* bias = zsel == 0 ? bq : (zsel == 1 ? bk : bvo);
  u16* outp = zsel == 0 ? qs : (zsel == 1 ? ksT : voT);
  const bool doSM = (zsel < 2);

  const int srow = tid >> 2;
  const int scol = (((tid & 3) ^ ((tid >> 3) & 3)) << 3);
  const u16* aptr0 = Az + (long)(m0 + srow) * 512 + scol;
  const u16* aptr1 = aptr0 + (long)64 * 512;
  const u16* bptr0 = Bz + (long)(bx * 128 + srow) * 512 + scol;
  const u16* bptr1 = bptr0 + (long)64 * 512;

  f32x4_t acc[4][4];
#pragma unroll
  for (int i = 0; i < 4; i++)
#pragma unroll
    for (int j = 0; j < 4; j++) acc[i][j] = (f32x4_t){0.f, 0.f, 0.f, 0.f};

  const int kg = lane >> 4;
  const int fr = lane & 15;

  int aoffL[4], boffL[4];
#pragma unroll
  for (int i = 0; i < 4; i++) {
    const int r = wm + i * 16 + fr;
    aoffL[i] = r * 32 + ((kg ^ ((r >> 1) & 3)) << 3);
  }
#pragma unroll
  for (int j = 0; j < 4; j++) {
    const int r = wn + j * 16 + fr;
    boffL[j] = 4096 + r * 32 + ((kg ^ ((r >> 1) & 3)) << 3);
  }

  auto stage = [&](int t, u16* nb) {
    const int ko = t * 32;
    gload16(aptr0 + ko, nb + tid * 8);
    gload16(aptr1 + ko, nb + (tid + 256) * 8);
    gload16(bptr0 + ko, nb + 4096 + tid * 8);
    gload16(bptr1 + ko, nb + 4096 + (tid + 256) * 8);
  };

  stage(0, smem);
  stage(1, smem + 8192);

  for (int t = 0; t < 16; t++) {
    if (t < 15) VMC(4);
    else        VMC(0);
    BAR();
    asm volatile("" ::: "memory");
    if (t + 2 < 16) stage(t + 2, smem + ((t + 2) % 3) * 8192);
    const u16* cb = smem + (t % 3) * 8192;
    bf16x8_t afr[4], bfr[4];
#pragma unroll
    for (int i = 0; i < 4; i++) afr[i] = *(const bf16x8_t*)&cb[aoffL[i]];
#pragma unroll
    for (int j = 0; j < 4; j++) bfr[j] = *(const bf16x8_t*)&cb[boffL[j]];
#pragma unroll
    for (int i = 0; i < 4; i++)
#pragma unroll
      for (int j = 0; j < 4; j++)
        acc[i][j] = __builtin_amdgcn_mfma_f32_16x16x32_bf16(afr[i], bfr[j], acc[i][j], 0, 0, 0);
  }
  __syncthreads();

  // ---- fused softmax over heads (zsel 0,1) ----
  if (doSM) {
    float* ex = (float*)smem;
    float* ex2 = ex + 4352;
    const int wmg = wave >> 1, wng = wave & 1;
    const int self = ((wmg * 2 + wng) * 64 + lane) * 17;
    const int part = ((wmg * 2 + (wng ^ 1)) * 64 + lane) * 17;
    float bj[4];
#pragma unroll
    for (int j = 0; j < 4; j++) bj[j] = bias[((wn >> 4) + j) * 512 + bx * 16 + fr];
#pragma unroll
    for (int i = 0; i < 4; i++)
#pragma unroll
      for (int j = 0; j < 4; j++)
#pragma unroll
        for (int r = 0; r < 4; r++) acc[i][j][r] += bj[j];
    float mx[16];
#pragma unroll
    for (int i = 0; i < 4; i++)
#pragma unroll
      for (int r = 0; r < 4; r++) {
        float m = acc[i][0][r];
#pragma unroll
        for (int j = 1; j < 4; j++) m = fmaxf(m, acc[i][j][r]);
        mx[i * 4 + r] = m;
      }
#pragma unroll
    for (int t = 0; t < 16; t++) ex[self + t] = mx[t];
    __syncthreads();
#pragma unroll
    for (int t = 0; t < 16; t++) mx[t] = fmaxf(mx[t], ex[part + t]);
    float sm[16];
#pragma unroll
    for (int t = 0; t < 16; t++) sm[t] = 0.f;
#pragma unroll
    for (int i = 0; i < 4; i++)
#pragma unroll
      for (int j = 0; j < 4; j++)
#pragma unroll
        for (int r = 0; r < 4; r++) {
          float p = __expf(acc[i][j][r] - mx[i * 4 + r]);
          acc[i][j][r] = p;
          sm[i * 4 + r] += p;
        }
#pragma unroll
    for (int t = 0; t < 16; t++) ex2[self + t] = sm[t];
    __syncthreads();
#pragma unroll
    for (int t = 0; t < 16; t++) sm[t] = 1.f / (sm[t] + ex2[part + t]);
#pragma unroll
    for (int i = 0; i < 4; i++)
#pragma unroll
      for (int j = 0; j < 4; j++)
#pragma unroll
        for (int r = 0; r < 4; r++) acc[i][j][r] *= sm[i * 4 + r];
    __syncthreads();
  }

  // ---- LDS-staged epilogue: Cs[128][136], nt stores ----
  constexpr int CW = 136;
  u16* Cs = smem;
  const int b = m0 >> 11, s0 = m0 & 2047;
  if (zsel == 0) {
#pragma unroll
    for (int j = 0; j < 4; j++) {
      const int c = wn + j * 16 + fr;
#pragma unroll
      for (int i = 0; i < 4; i++) {
        const int rbase = wm + i * 16 + ((lane >> 4) << 2);
#pragma unroll
        for (int r = 0; r < 4; r++)
          Cs[(rbase + r) * CW + c] = f2bf(acc[i][j][r]);
      }
    }
    __syncthreads();
    const long base = (long)b * 8388608 + (long)s0 * 4096 + bx * 128;
#pragma unroll
    for (int it = 0; it < 8; it++) {
      const int idx = it * 256 + tid;
      const int row = idx >> 4, ch = idx & 15;
      nts16(&outp[base + (long)row * 4096 + ch * 8], *(const u32x4*)&Cs[row * CW + ch * 8]);
    }
  } else {
#pragma unroll
    for (int j = 0; j < 4; j++) {
      const int c = wn + j * 16 + fr;
      const float bb = doSM ? 0.f : bias[((wn >> 4) + j) * 512 + bx * 16 + fr];
#pragma unroll
      for (int i = 0; i < 4; i++) {
        us4 w;
#pragma unroll
        for (int r = 0; r < 4; r++) w.v[r] = f2bf(acc[i][j][r] + bb);
        *(us4*)&Cs[c * CW + wm + i * 16 + ((lane >> 4) << 2)] = w;
      }
    }
    __syncthreads();
#pragma unroll
    for (int it = 0; it < 8; it++) {
      const int idx = it * 256 + tid;
      const int row = idx >> 4, ch = idx & 15;
      const long base = (long)(b * 8 + (row >> 4)) * 1048576 +
                        (long)(bx * 16 + (row & 15)) * 2048 + s0;
      nts16(&outp[base + ch * 8], *(const u32x4*)&Cs[row * CW + ch * 8]);
    }
  }
}

// ===== 128x128 core: M_W2K (ks@voT -> W2Pt), M_WVO (Wv@Wo2 -> WvoT), M_FINAL =====
#define M_W2K   2
#define M_WVO   3
#define M_FINAL 4

template<int MODE>
__global__ __launch_bounds__(256, 2)
void gemm_kernel(const u16* __restrict__ A, long sAz, int lda,
                 const u16* __restrict__ B, long sBz, int ldb,
                 void* __restrict__ Cv, long sCz, int ldc,
                 int nx, int ny, int K)
{
  __shared__ __align__(16) u16 smem[24576];

  const int nwg = gridDim.x;
  const int chunk = nwg >> 3;
  const int bid = blockIdx.x;
  const int wg = (bid & 7) * chunk + (bid >> 3);
  const int nxy = nx * ny;
  const int z = wg / nxy;
  const int rem = wg - z * nxy;
  const int by = rem / nx;
  const int bx = rem - by * nx;

  const int tid = threadIdx.x;
  const int lane = tid & 63;
  const int wave = tid >> 6;
  const int wm = (wave >> 1) * 64;
  const int wn = (wave & 1) * 64;
  const int m0 = by * 128;
  const int n0 = bx * 128;

  const u16* Az; const u16* Bz;
  if constexpr (MODE == M_FINAL) {
    Az = A + (long)(z >> 2) * 8388608 + (z & 3) * 1024;
    Bz = B + (long)(z >> 2) * 2097152 + (z & 3) * 1024;
  } else {
    Az = A + (long)z * sAz;
    Bz = B + (long)z * sBz;
  }

  const int srow = tid >> 2;
  const int scol = (((tid & 3) ^ ((tid >> 3) & 3)) << 3);
  const u16* aptr0 = Az + (long)(m0 + srow) * lda + scol;
  const u16* aptr1 = aptr0 + (long)64 * lda;
  const u16* bptr0 = Bz + (long)(n0 + srow) * ldb + scol;
  const u16* bptr1 = bptr0 + (long)64 * ldb;

  f32x4_t acc[4][4];
#pragma unroll
  for (int i = 0; i < 4; i++)
#pragma unroll
    for (int j = 0; j < 4; j++) acc[i][j] = (f32x4_t){0.f, 0.f, 0.f, 0.f};

  const int kg = lane >> 4;
  const int fr = lane & 15;
  const int nt = K >> 5;

  int aoffL[4], boffL[4];
#pragma unroll
  for (int i = 0; i < 4; i++) {
    const int r = wm + i * 16 + fr;
    aoffL[i] = r * 32 + ((kg ^ ((r >> 1) & 3)) << 3);
  }
#pragma unroll
  for (int j = 0; j < 4; j++) {
    const int r = wn + j * 16 + fr;
    boffL[j] = 4096 + r * 32 + ((kg ^ ((r >> 1) & 3)) << 3);
  }

  auto stage = [&](int t, u16* nb) {
    const int ko = t * 32;
    gload16(aptr0 + ko, nb + tid * 8);
    gload16(aptr1 + ko, nb + (tid + 256) * 8);
    gload16(bptr0 + ko, nb + 4096 + tid * 8);
    gload16(bptr1 + ko, nb + 4096 + (tid + 256) * 8);
  };

  stage(0, smem);
  stage(1, smem + 8192);

  for (int t = 0; t < nt; t++) {
    if (t < nt - 1) VMC(4);
    else            VMC(0);
    BAR();
    asm volatile("" ::: "memory");
    if (t + 2 < nt) stage(t + 2, smem + ((t + 2) % 3) * 8192);
    const u16* cb = smem + (t % 3) * 8192;
    bf16x8_t afr[4], bfr[4];
#pragma unroll
    for (int i = 0; i < 4; i++) afr[i] = *(const bf16x8_t*)&cb[aoffL[i]];
#pragma unroll
    for (int j = 0; j < 4; j++) bfr[j] = *(const bf16x8_t*)&cb[boffL[j]];
#pragma unroll
    for (int i = 0; i < 4; i++)
#pragma unroll
      for (int j = 0; j < 4; j++)
        acc[i][j] = __builtin_amdgcn_mfma_f32_16x16x32_bf16(afr[i], bfr[j], acc[i][j], 0, 0, 0);
  }
  __syncthreads();

  if constexpr (MODE == M_FINAL) {
    float* o = (float*)Cv + (long)(z & 3) * 4194304 + (long)(z >> 2) * 1048576;
#pragma unroll
    for (int i = 0; i < 4; i++) {
      const int rbase = m0 + wm + i * 16 + ((lane >> 4) << 2);
#pragma unroll
      for (int j = 0; j < 4; j++) {
        const int gc = n0 + wn + j * 16 + fr;
#pragma unroll
        for (int r = 0; r < 4; r++)
          __builtin_nontemporal_store(acc[i][j][r], &o[(long)(rbase + r) * ldc + gc]);
      }
    }
    return;
  }

  // transposed staging: Cs[row = tile col c][col = m_local]
  constexpr int CW = 136;
  u16* Cs = smem;
#pragma unroll
  for (int j = 0; j < 4; j++) {
    const int c = wn + j * 16 + fr;
#pragma unroll
    for (int i = 0; i < 4; i++) {
      us4 w;
#pragma unroll
      for (int r = 0; r < 4; r++) w.v[r] = f2bf(acc[i][j][r]);
      *(us4*)&Cs[c * CW + wm + i * 16 + ((lane >> 4) << 2)] = w;
    }
  }
  __syncthreads();

  u16* dst = (u16*)Cv;
  if constexpr (MODE == M_W2K) {
    // W2Pt[b][f][perm(h,d)]: z=b*8+h, Cs row = f-col, col = d_local
    const int b = z >> 3, h = z & 7;
    const long base0 = (long)b * 2097152 + (long)n0 * 4096 + ((m0 >> 4) << 7) + h * 16;
#pragma unroll
    for (int it = 0; it < 4; it++) {
      const int idx = it * 256 + tid;
      const int row = idx >> 3, ch = idx & 7;
      const long base = base0 + (long)row * 4096 + ch * 128;
      nts16(&dst[base], *(const u32x4*)&Cs[row * CW + ch * 16]);
      nts16(&dst[base + 8], *(const u32x4*)&Cs[row * CW + ch * 16 + 8]);
    }
  } else {  // M_WVO: WvoT[(f>>4)*128 + h*16 + (f&15)][d], z = h
    const int h = z;
#pragma unroll
    for (int it = 0; it < 8; it++) {
      const int idx = it * 256 + tid;
      const int row = idx >> 4, ch = idx & 15;   // row = f-col 0..127
      const int f = n0 + row;
      const long rowp = ((f >> 4) << 7) + h * 16 + (f & 15);
      nts16(&dst[rowp * 512 + m0 + ch * 8], *(const u32x4*)&Cs[row * CW + ch * 8]);
    }
  }
}

// ---------------- support kernels ----------------
__global__ void cvt3_kernel(const float* __restrict__ q, const float* __restrict__ k,
                            const float* __restrict__ v, u16* __restrict__ qb,
                            u16* __restrict__ kb, u16* __restrict__ vb) {
  const int arr = blockIdx.x >> 11;
  const int lb = blockIdx.x & 2047;
  const float* in = arr == 0 ? q : (arr == 1 ? k : v);
  u16* out = arr == 0 ? qb : (arr == 1 ? kb : vb);
  const long i = ((long)lb * 256 + threadIdx.x) * 8;
  float4 a = *(const float4*)(in + i);
  float4 b = *(const float4*)(in + i + 4);
  u16 t[8] = {f2bf(a.x), f2bf(a.y), f2bf(a.z), f2bf(a.w),
              f2bf(b.x), f2bf(b.y), f2bf(b.z), f2bf(b.w)};
  u32x4 w; __builtin_memcpy(&w, t, 16);
  nts16(out + i, w);
}

// plain fp32->bf16 of Wv (2M elems)
__global__ void cvtw_kernel(const float* __restrict__ in, u16* __restrict__ out) {
  const long i = ((long)blockIdx.x * 256 + threadIdx.x) * 8;
  float4 a = *(const float4*)(in + i);
  float4 b = *(const float4*)(in + i + 4);
  u16 t[8] = {f2bf(a.x), f2bf(a.y), f2bf(a.z), f2bf(a.w),
              f2bf(b.x), f2bf(b.y), f2bf(b.z), f2bf(b.w)};
  u32x4 w; __builtin_memcpy(&w, t, 16);
  nts16(out + i, w);
}

// WT[(e>>4)*128 + h*16 + (e&15)][d] = bf16(W[h][d][e]); arr = z>>3 in {0,1}
__global__ void tcvt3_kernel(const float* __restrict__ Wq, const float* __restrict__ Wk,
                             const float* __restrict__ Wv, u16* __restrict__ WqT,
                             u16* __restrict__ WkT, u16* __restrict__ WvT)
{
  __shared__ float tile[32][33];
  const int arr = blockIdx.z >> 3;
  const int h = blockIdx.z & 7;
  const float* in = (arr == 0 ? Wq : (arr == 1 ? Wk : Wv)) + (long)h * 262144;
  u16* out = arr == 0 ? WqT : (arr == 1 ? WkT : WvT);
  const int c0 = blockIdx.x * 32, r0 = blockIdx.y * 32;
#pragma unroll
  for (int yy = threadIdx.y; yy < 32; yy += 8)
    tile[yy][threadIdx.x] = in[(long)(r0 + yy) * 512 + c0 + threadIdx.x];
  __syncthreads();
#pragma unroll
  for (int yy = threadIdx.y; yy < 32; yy += 8) {
    const int e = c0 + yy;
    const int rowp = ((e >> 4) << 7) + h * 16 + (e & 15);
    out[(long)rowp * 512 + r0 + threadIdx.x] = f2bf(tile[threadIdx.x][yy]);
  }
}

// WoT2[h][f][e] = bf16(Wo[e*8+h][f])
__global__ void tcvt_wo2(const float* __restrict__ in, u16* __restrict__ out) {
  __shared__ float tile[32][33];
  const int h = blockIdx.z;
  const int e0 = blockIdx.x * 32, f0 = blockIdx.y * 32;
#pragma unroll
  for (int yy = threadIdx.y; yy < 32; yy += 8)
    tile[yy][threadIdx.x] = in[(long)((e0 + yy) * 8 + h) * 512 + f0 + threadIdx.x];
  __syncthreads();
#pragma unroll
  for (int yy = threadIdx.y; yy < 32; yy += 8)
    out[(long)h * 262144 + (long)(f0 + yy) * 512 + e0 + threadIdx.x] =
        f2bf(tile[threadIdx.x][yy]);
}

// bvo[h*512+f] = sum_e bv[h*512+e] * WoT2[h][f][e]; grid 16x256
__global__ void bvo_kernel(const float* __restrict__ bv, const u16* __restrict__ WoT2,
                           float* __restrict__ bvo) {
  const int gid = blockIdx.x * 256 + threadIdx.x;
  const int h = gid >> 9, f = gid & 511;
  const u16* w = WoT2 + (long)h * 262144 + (long)f * 512;
  const float* bvh = bv + h * 512;
  float s = 0.f;
  for (int e = 0; e < 512; e += 4) {
    us4 ww = *(const us4*)(w + e);
    s += bvh[e] * bf2f(ww.v[0]) + bvh[e + 1] * bf2f(ww.v[1]) +
         bvh[e + 2] * bf2f(ww.v[2]) + bvh[e + 3] * bf2f(ww.v[3]);
  }
  bvo[gid] = s;
}

// sum 4 fp32 K-split partials + bias -> fp32 out
__global__ void reduce4_kernel(const float* __restrict__ p, const float* __restrict__ bo,
                               float* __restrict__ out)
{
  const long S = 8192L * 512;
  const long i4 = ((long)blockIdx.x * 256 + threadIdx.x) * 4;
  float4 a = *(const float4*)(p + i4);
  float4 b = *(const float4*)(p + S + i4);
  float4 c = *(const float4*)(p + 2 * S + i4);
  float4 d = *(const float4*)(p + 3 * S + i4);
  float4 bb = *(const float4*)(bo + (i4 & 511));
  float4 r;
  r.x = a.x + b.x + c.x + d.x + bb.x;
  r.y = a.y + b.y + c.y + d.y + bb.y;
  r.z = a.z + b.z + c.z + d.z + bb.z;
  r.w = a.w + b.w + c.w + d.w + bb.w;
  u32x4 w; __builtin_memcpy(&w, &r, 16);
  nts16(out + i4, w);
}

extern "C" void kernel_launch(void* const* d_in, const int* in_sizes, int n_in,
                              void* d_out, int out_size, void* d_ws, size_t ws_size,
                              hipStream_t stream) {
  const float* q  = (const float*)d_in[0];
  const float* k  = (const float*)d_in[1];
  const float* v  = (const float*)d_in[2];
  const float* Wq = (const float*)d_in[3];
  const float* bq = (const float*)d_in[4];
  const float* Wk = (const float*)d_in[5];
  const float* bk = (const float*)d_in[6];
  const float* Wv = (const float*)d_in[7];
  const float* bv = (const float*)d_in[8];
  const float* Wo = (const float*)d_in[9];
  const float* bo = (const float*)d_in[10];
  float* outp = (float*)d_out;

  char* ws = (char*)d_ws;
  // layout (peak 212 MiB), liveness verified per stage:
  u16* qs    = (u16*)(ws);                  //   0- 64 qsP (A out; final in)
  u16* ksT   = (u16*)(ws + (64L  << 20));   //  64-128 (A out; W2K in)
  u16* voT   = (u16*)(ws + (128L << 20));   // 128-192 (B out; W2K in)
  u16* qb    = (u16*)(ws + (128L << 20));   // 128-136 in voT; dead after A
  u16* kb    = (u16*)(ws + (136L << 20));   // 136-144 in voT; dead after A
  u16* WqT   = (u16*)(ws + (144L << 20));   // 144-148 in voT; dead after A
  u16* WkT   = (u16*)(ws + (148L << 20));   // 148-152 in voT; dead after A
  float* Pf  = (float*)(ws + (128L << 20)); // 128-192 final partials (voT dead)
  u16* vb    = (u16*)(ws + (192L << 20));   // 192-200 (B in); dead after B
  u16* Wvb   = (u16*)(ws + (200L << 20));   // 200-204 (WVO in); dead after WVO
  u16* WvoT  = (u16*)(ws + (204L << 20));   // 204-208 (WVO out; B in); dead after B
  u16* W2Pt  = (u16*)(ws + (192L << 20));   // 192-208 (W2K out; final in)
  u16* WoT2  = (u16*)(ws + (208L << 20));   // 208-212 (WVO/bvo in)
  float* bvo = outp;                        // 16 KiB scratch; overwritten by reduce4

  // 1. input converts
  cvt3_kernel<<<6144, 256, 0, stream>>>(q, k, v, qb, kb, vb);
  cvtw_kernel<<<1024, 256, 0, stream>>>(Wv, Wvb);

  // 2. weight transposes (Q,K interleaved; Wo per-head)
  dim3 tb(32, 8, 1);
  tcvt3_kernel<<<dim3(16, 16, 16), tb, 0, stream>>>(Wq, Wk, nullptr, WqT, WkT, nullptr);
  tcvt_wo2<<<dim3(16, 16, 8), tb, 0, stream>>>(Wo, WoT2);

  // 3. Wvo[h][d][f] = sum_e Wvb[h][d][e]*WoT2[h][f][e] -> WvoT (interleaved rows)
  gemm_kernel<M_WVO><<<128, 256, 0, stream>>>(
      Wvb, 262144, 512, WoT2, 262144, 512, WvoT, 0, 0, 4, 4, 512);
  // 4. bvo[h][f] = sum_e bv*Wo2 (staged in d_out)
  bvo_kernel<<<16, 256, 0, stream>>>(bv, WoT2, bvo);

  // 5. launch A: Q+K (softmax fused); launch B: VO-proj
  proj3_kernel<<<4096, 256, 0, stream>>>(qb, kb, vb, WqT, WkT, WvoT,
                                         bq, bk, bvo, qs, ksT, voT, 0);
  proj3_kernel<<<2048, 256, 0, stream>>>(qb, kb, vb, WqT, WkT, WvoT,
                                         bq, bk, bvo, qs, ksT, voT, 2);

  // 6. W2Pt[b][f][perm(h,d)] = sum_s ksT[b,h][d][s]*voT[b,h][f][s]; K=2048
  gemm_kernel<M_W2K><<<512, 256, 0, stream>>>(
      ksT, 1048576, 2048, voT, 1048576, 2048, W2Pt, 0, 0, 4, 4, 2048);

  // 7. final partials: K=4096 split 4x1024
  gemm_kernel<M_FINAL><<<1024, 256, 0, stream>>>(
      qs, 0, 4096, W2Pt, 0, 4096, Pf, 0, 512, 4, 16, 1024);

  // 8. reduce partials + bias -> fp32 out
  reduce4_kernel<<<4096, 256, 0, stream>>>(Pf, bo, outp);
}

// Round 15
// 311.686 us; speedup vs baseline: 1.1522x; 1.1522x over previous
//
#include <hip/hip_runtime.h>
#include <hip/hip_bf16.h>

typedef unsigned short u16;
typedef __bf16 bf16x8_t __attribute__((ext_vector_type(8)));
typedef float f32x4_t __attribute__((ext_vector_type(4)));

struct alignas(8) us4 { u16 v[4]; };

__device__ __forceinline__ u16 f2bf(float f) {
  __hip_bfloat16 h = __float2bfloat16(f);
  u16 u; __builtin_memcpy(&u, &h, 2); return u;
}

__device__ __forceinline__ void gload16(const u16* g, u16* l) {
  __builtin_amdgcn_global_load_lds(
      (const __attribute__((address_space(1))) void*)g,
      (__attribute__((address_space(3))) void*)l, 16, 0, 0);
}

#define BAR()  __builtin_amdgcn_s_barrier()
#define VMC(n) asm volatile("s_waitcnt vmcnt(%0)" :: "i"(n) : "memory")

// ============ projection kernel (zsel picks q/k/v) ============
// launch A: grid 4096, zoff 0 -> zsel {0,1} (Q,K).  launch B: grid 2048,
// zoff 2 -> zsel 2 (V).  128x128 tile, BK=32, 4-buf depth-3 counted-vmcnt
// loop (vmcnt(8) steady state; tail 4->0), chunk-XOR swizzled LDS both-sides.
// Weights pre-interleaved (col n -> h=(n>>4)&7, e=(n>>7)*16+(n&15)).
// zsel 0: softmax + qsP[b][s][n]. zsel 1: softmax + [b,h,e,s].
// zsel 2: bias only + [b,h,e,s].
// ALIASING CONTRACT: launch A reads qb/kb/W{q,k}T at 128-152 MiB and writes
// 0-128; launch B writes vsT 128-192 (A's inputs dead by then).
__global__ __launch_bounds__(256, 2)
void proj3_kernel(const u16* __restrict__ qb, const u16* __restrict__ kb,
                  const u16* __restrict__ vb, const u16* __restrict__ WqT,
                  const u16* __restrict__ WkT, const u16* __restrict__ WvT,
                  const float* __restrict__ bq, const float* __restrict__ bk,
                  const float* __restrict__ bv, u16* __restrict__ qs,
                  u16* __restrict__ ksT, u16* __restrict__ vsT, int zoff)
{
  __shared__ __align__(16) u16 smem[32768];  // 4 x 8192 staging bufs; reused

  const int bid = blockIdx.x;
  const int chunk = gridDim.x >> 3;
  const int wg = (bid & 7) * chunk + (bid >> 3);   // XCD-bijective (grid % 8 == 0)
  const int zsel = zoff + (wg >> 11);
  const int rem = wg & 2047;
  const int by = rem >> 5;
  const int bx = rem & 31;

  const int tid = threadIdx.x;
  const int lane = tid & 63;
  const int wave = tid >> 6;
  const int wm = (wave >> 1) * 64;
  const int wn = (wave & 1) * 64;
  const int m0 = by * 128;

  const u16* Az = zsel == 0 ? qb : (zsel == 1 ? kb : vb);
  const u16* Bz = zsel == 0 ? WqT : (zsel == 1 ? WkT : WvT);
  const float* bias = zsel == 0 ? bq : (zsel == 1 ? bk : bv);
  u16* outp = zsel == 0 ? qs : (zsel == 1 ? ksT : vsT);
  const bool doSM = (zsel < 2);

  const int srow = tid >> 2;
  const int scol = (((tid & 3) ^ ((tid >> 3) & 3)) << 3);
  const u16* aptr0 = Az + (long)(m0 + srow) * 512 + scol;
  const u16* aptr1 = aptr0 + (long)64 * 512;
  const u16* bptr0 = Bz + (long)(bx * 128 + srow) * 512 + scol;
  const u16* bptr1 = bptr0 + (long)64 * 512;

  f32x4_t acc[4][4];
#pragma unroll
  for (int i = 0; i < 4; i++)
#pragma unroll
    for (int j = 0; j < 4; j++) acc[i][j] = (f32x4_t){0.f, 0.f, 0.f, 0.f};

  const int kg = lane >> 4;
  const int fr = lane & 15;

  int aoffL[4], boffL[4];
#pragma unroll
  for (int i = 0; i < 4; i++) {
    const int r = wm + i * 16 + fr;
    aoffL[i] = r * 32 + ((kg ^ ((r >> 1) & 3)) << 3);
  }
#pragma unroll
  for (int j = 0; j < 4; j++) {
    const int r = wn + j * 16 + fr;
    boffL[j] = 4096 + r * 32 + ((kg ^ ((r >> 1) & 3)) << 3);
  }

  auto stage = [&](int t, u16* nb) {
    const int ko = t * 32;
    gload16(aptr0 + ko, nb + tid * 8);
    gload16(aptr1 + ko, nb + (tid + 256) * 8);
    gload16(bptr0 + ko, nb + 4096 + tid * 8);
    gload16(bptr1 + ko, nb + 4096 + (tid + 256) * 8);
  };

  stage(0, smem);
  stage(1, smem + 8192);
  stage(2, smem + 16384);

  for (int t = 0; t < 16; t++) {
    if (t < 14)      VMC(8);
    else if (t == 14) VMC(4);
    else              VMC(0);
    BAR();
    asm volatile("" ::: "memory");
    if (t + 3 < 16) stage(t + 3, smem + ((t + 3) & 3) * 8192);
    const u16* cb = smem + (t & 3) * 8192;
    bf16x8_t afr[4], bfr[4];
#pragma unroll
    for (int i = 0; i < 4; i++) afr[i] = *(const bf16x8_t*)&cb[aoffL[i]];
#pragma unroll
    for (int j = 0; j < 4; j++) bfr[j] = *(const bf16x8_t*)&cb[boffL[j]];
#pragma unroll
    for (int i = 0; i < 4; i++)
#pragma unroll
      for (int j = 0; j < 4; j++)
        acc[i][j] = __builtin_amdgcn_mfma_f32_16x16x32_bf16(afr[i], bfr[j], acc[i][j], 0, 0, 0);
  }
  __syncthreads();  // full drain before smem reuse

  // ---- fused softmax over heads (zsel 0,1) ----
  if (doSM) {
    float* ex = (float*)smem;          // stride 17 -> conflict-free
    float* ex2 = ex + 4352;
    const int wmg = wave >> 1, wng = wave & 1;
    const int self = ((wmg * 2 + wng) * 64 + lane) * 17;
    const int part = ((wmg * 2 + (wng ^ 1)) * 64 + lane) * 17;
    float bj[4];
#pragma unroll
    for (int j = 0; j < 4; j++) bj[j] = bias[((wn >> 4) + j) * 512 + bx * 16 + fr];
#pragma unroll
    for (int i = 0; i < 4; i++)
#pragma unroll
      for (int j = 0; j < 4; j++)
#pragma unroll
        for (int r = 0; r < 4; r++) acc[i][j][r] += bj[j];
    float mx[16];
#pragma unroll
    for (int i = 0; i < 4; i++)
#pragma unroll
      for (int r = 0; r < 4; r++) {
        float m = acc[i][0][r];
#pragma unroll
        for (int j = 1; j < 4; j++) m = fmaxf(m, acc[i][j][r]);
        mx[i * 4 + r] = m;
      }
#pragma unroll
    for (int t = 0; t < 16; t++) ex[self + t] = mx[t];
    __syncthreads();
#pragma unroll
    for (int t = 0; t < 16; t++) mx[t] = fmaxf(mx[t], ex[part + t]);
    float sm[16];
#pragma unroll
    for (int t = 0; t < 16; t++) sm[t] = 0.f;
#pragma unroll
    for (int i = 0; i < 4; i++)
#pragma unroll
      for (int j = 0; j < 4; j++)
#pragma unroll
        for (int r = 0; r < 4; r++) {
          float p = __expf(acc[i][j][r] - mx[i * 4 + r]);
          acc[i][j][r] = p;
          sm[i * 4 + r] += p;
        }
#pragma unroll
    for (int t = 0; t < 16; t++) ex2[self + t] = sm[t];
    __syncthreads();
#pragma unroll
    for (int t = 0; t < 16; t++) sm[t] = 1.f / (sm[t] + ex2[part + t]);
#pragma unroll
    for (int i = 0; i < 4; i++)
#pragma unroll
      for (int j = 0; j < 4; j++)
#pragma unroll
        for (int r = 0; r < 4; r++) acc[i][j][r] *= sm[i * 4 + r];
    __syncthreads();
  }

  // ---- LDS-staged epilogue: Cs[128][136] ----
  constexpr int CW = 136;
  u16* Cs = smem;
  const int b = m0 >> 11, s0 = m0 & 2047;
  if (zsel == 0) {
    // qsP[b][s][bx*128 + c]
#pragma unroll
    for (int j = 0; j < 4; j++) {
      const int c = wn + j * 16 + fr;
#pragma unroll
      for (int i = 0; i < 4; i++) {
        const int rbase = wm + i * 16 + ((lane >> 4) << 2);
#pragma unroll
        for (int r = 0; r < 4; r++)
          Cs[(rbase + r) * CW + c] = f2bf(acc[i][j][r]);
      }
    }
    __syncthreads();
    const long base = (long)b * 8388608 + (long)s0 * 4096 + bx * 128;
#pragma unroll
    for (int it = 0; it < 8; it++) {
      const int idx = it * 256 + tid;
      const int row = idx >> 4, ch = idx & 15;
      *(uint4*)&outp[base + (long)row * 4096 + ch * 8] = *(const uint4*)&Cs[row * CW + ch * 8];
    }
  } else {
    // transposed tile: Cs[row = tile col c][col = s]; bias only for v (zsel 2)
#pragma unroll
    for (int j = 0; j < 4; j++) {
      const int c = wn + j * 16 + fr;
      const float bb = doSM ? 0.f : bias[((wn >> 4) + j) * 512 + bx * 16 + fr];
#pragma unroll
      for (int i = 0; i < 4; i++) {
        us4 w;
#pragma unroll
        for (int r = 0; r < 4; r++) w.v[r] = f2bf(acc[i][j][r] + bb);
        *(us4*)&Cs[c * CW + wm + i * 16 + ((lane >> 4) << 2)] = w;
      }
    }
    __syncthreads();
#pragma unroll
    for (int it = 0; it < 8; it++) {
      const int idx = it * 256 + tid;
      const int row = idx >> 4, ch = idx & 15;
      const long base = (long)(b * 8 + (row >> 4)) * 1048576 +
                        (long)(bx * 16 + (row & 15)) * 2048 + s0;
      *(uint4*)&outp[base + ch * 8] = *(const uint4*)&Cs[row * CW + ch * 8];
    }
  }
}

// ================= 128x128 core for ctx / W2 / final =================
#define M_PLAIN 2
#define M_W2    3
#define M_FINAL 4
#define M_CTXS  5

template<int MODE>
__global__ __launch_bounds__(256, 2)
void gemm_kernel(const u16* __restrict__ A, long sAz, int lda,
                 const u16* __restrict__ B, long sBz, int ldb,
                 void* __restrict__ Cv, long sCz, int ldc,
                 int nx, int ny, int K)
{
  __shared__ __align__(16) u16 smem[32768];  // 4 x 8192 staging bufs; reused

  const int nwg = gridDim.x;
  const int chunk = nwg >> 3;
  const int bid = blockIdx.x;
  const int wg = (bid & 7) * chunk + (bid >> 3);
  const int nxy = nx * ny;
  const int z = wg / nxy;
  const int rem = wg - z * nxy;
  const int by = rem / nx;
  const int bx = rem - by * nx;

  const int tid = threadIdx.x;
  const int lane = tid & 63;
  const int wave = tid >> 6;
  const int wm = (wave >> 1) * 64;
  const int wn = (wave & 1) * 64;
  const int m0 = by * 128;
  const int n0 = bx * 128;

  const u16* Az; const u16* Bz;
  if constexpr (MODE == M_CTXS) {
    const int bh = z & 31, kc = z >> 5;
    Az = A + (long)bh * 1048576 + kc * 1024;
    Bz = B + (long)bh * 1048576 + kc * 1024;
  } else if constexpr (MODE == M_W2) {
    Az = A + (long)z * 262144;
    Bz = B + (long)(z & 7) * 262144;
  } else if constexpr (MODE == M_FINAL) {
    Az = A + (long)(z >> 2) * 8388608 + (z & 3) * 1024;
    Bz = B + (long)(z >> 2) * 2097152 + (z & 3) * 1024;
  } else {
    Az = A + (long)z * sAz;
    Bz = B + (long)z * sBz;
  }

  const int srow = tid >> 2;
  const int scol = (((tid & 3) ^ ((tid >> 3) & 3)) << 3);
  const u16* aptr0 = Az + (long)(m0 + srow) * lda + scol;
  const u16* aptr1 = aptr0 + (long)64 * lda;
  const u16* bptr0 = Bz + (long)(n0 + srow) * ldb + scol;
  const u16* bptr1 = bptr0 + (long)64 * ldb;

  f32x4_t acc[4][4];
#pragma unroll
  for (int i = 0; i < 4; i++)
#pragma unroll
    for (int j = 0; j < 4; j++) acc[i][j] = (f32x4_t){0.f, 0.f, 0.f, 0.f};

  const int kg = lane >> 4;
  const int fr = lane & 15;
  const int nt = K >> 5;

  int aoffL[4], boffL[4];
#pragma unroll
  for (int i = 0; i < 4; i++) {
    const int r = wm + i * 16 + fr;
    aoffL[i] = r * 32 + ((kg ^ ((r >> 1) & 3)) << 3);
  }
#pragma unroll
  for (int j = 0; j < 4; j++) {
    const int r = wn + j * 16 + fr;
    boffL[j] = 4096 + r * 32 + ((kg ^ ((r >> 1) & 3)) << 3);
  }

  auto stage = [&](int t, u16* nb) {
    const int ko = t * 32;
    gload16(aptr0 + ko, nb + tid * 8);
    gload16(aptr1 + ko, nb + (tid + 256) * 8);
    gload16(bptr0 + ko, nb + 4096 + tid * 8);
    gload16(bptr1 + ko, nb + 4096 + (tid + 256) * 8);
  };

  stage(0, smem);
  stage(1, smem + 8192);
  stage(2, smem + 16384);

  for (int t = 0; t < nt; t++) {
    if (t < nt - 2)      VMC(8);
    else if (t == nt - 2) VMC(4);
    else                  VMC(0);
    BAR();
    asm volatile("" ::: "memory");
    if (t + 3 < nt) stage(t + 3, smem + ((t + 3) & 3) * 8192);
    const u16* cb = smem + (t & 3) * 8192;
    bf16x8_t afr[4], bfr[4];
#pragma unroll
    for (int i = 0; i < 4; i++) afr[i] = *(const bf16x8_t*)&cb[aoffL[i]];
#pragma unroll
    for (int j = 0; j < 4; j++) bfr[j] = *(const bf16x8_t*)&cb[boffL[j]];
#pragma unroll
    for (int i = 0; i < 4; i++)
#pragma unroll
      for (int j = 0; j < 4; j++)
        acc[i][j] = __builtin_amdgcn_mfma_f32_16x16x32_bf16(afr[i], bfr[j], acc[i][j], 0, 0, 0);
  }
  __syncthreads();

  if constexpr (MODE == M_FINAL || MODE == M_CTXS) {
    float* o;
    if constexpr (MODE == M_FINAL)
      o = (float*)Cv + (long)(z & 3) * 4194304 + (long)(z >> 2) * 1048576;
    else
      o = (float*)Cv + (long)z * 262144;
#pragma unroll
    for (int i = 0; i < 4; i++) {
      const int rbase = m0 + wm + i * 16 + ((lane >> 4) << 2);
#pragma unroll
      for (int j = 0; j < 4; j++) {
        const int gc = n0 + wn + j * 16 + fr;
#pragma unroll
        for (int r = 0; r < 4; r++)
          o[(long)(rbase + r) * ldc + gc] = acc[i][j][r];
      }
    }
    return;
  }

  constexpr int CW = 136;
  u16* Cs = smem;
  if constexpr (MODE == M_W2) {
#pragma unroll
    for (int j = 0; j < 4; j++) {
      const int c = wn + j * 16 + fr;
#pragma unroll
      for (int i = 0; i < 4; i++) {
        us4 w;
#pragma unroll
        for (int r = 0; r < 4; r++) w.v[r] = f2bf(acc[i][j][r]);
        *(us4*)&Cs[c * CW + wm + i * 16 + ((lane >> 4) << 2)] = w;
      }
    }
  } else {
#pragma unroll
    for (int j = 0; j < 4; j++) {
      const int c = wn + j * 16 + fr;
#pragma unroll
      for (int i = 0; i < 4; i++) {
        const int rbase = wm + i * 16 + ((lane >> 4) << 2);
#pragma unroll
        for (int r = 0; r < 4; r++)
          Cs[(rbase + r) * CW + c] = f2bf(acc[i][j][r]);
      }
    }
  }
  __syncthreads();

  u16* dst = (u16*)Cv;
  if constexpr (MODE == M_W2) {
    const int b = z >> 3, h = z & 7;
    const long base0 = (long)b * 2097152 + (long)n0 * 4096 + ((m0 >> 4) << 7) + h * 16;
#pragma unroll
    for (int it = 0; it < 4; it++) {
      const int idx = it * 256 + tid;
      const int row = idx >> 3, ch = idx & 7;
      const long base = base0 + (long)row * 4096 + ch * 128;
      *(uint4*)&dst[base] = *(const uint4*)&Cs[row * CW + ch * 16];
      *(uint4*)&dst[base + 8] = *(const uint4*)&Cs[row * CW + ch * 16 + 8];
    }
  } else {  // M_PLAIN
    const long base = (long)z * sCz + (long)m0 * ldc + n0;
#pragma unroll
    for (int it = 0; it < 8; it++) {
      const int idx = it * 256 + tid;
      const int row = idx >> 4, ch = idx & 15;
      *(uint4*)&dst[base + (long)row * ldc + ch * 8] = *(const uint4*)&Cs[row * CW + ch * 8];
    }
  }
}

// ---------------- support kernels ----------------
__global__ void cvt3_kernel(const float* __restrict__ q, const float* __restrict__ k,
                            const float* __restrict__ v, u16* __restrict__ qb,
                            u16* __restrict__ kb, u16* __restrict__ vb) {
  const int arr = blockIdx.x >> 11;
  const int lb = blockIdx.x & 2047;
  const float* in = arr == 0 ? q : (arr == 1 ? k : v);
  u16* out = arr == 0 ? qb : (arr == 1 ? kb : vb);
  const long i = ((long)lb * 256 + threadIdx.x) * 8;
  float4 a = *(const float4*)(in + i);
  float4 b = *(const float4*)(in + i + 4);
  u16 t[8] = {f2bf(a.x), f2bf(a.y), f2bf(a.z), f2bf(a.w),
              f2bf(b.x), f2bf(b.y), f2bf(b.z), f2bf(b.w)};
  uint4 w; __builtin_memcpy(&w, t, 16);
  *(uint4*)(out + i) = w;
}

// WT[(e>>4)*128 + h*16 + (e&15)][d] = bf16(W[h][d][e])
__global__ void tcvt3_kernel(const float* __restrict__ Wq, const float* __restrict__ Wk,
                             const float* __restrict__ Wv, u16* __restrict__ WqT,
                             u16* __restrict__ WkT, u16* __restrict__ WvT)
{
  __shared__ float tile[32][33];
  const int arr = blockIdx.z >> 3;
  const int h = blockIdx.z & 7;
  const float* in = (arr == 0 ? Wq : (arr == 1 ? Wk : Wv)) + (long)h * 262144;
  u16* out = arr == 0 ? WqT : (arr == 1 ? WkT : WvT);
  const int c0 = blockIdx.x * 32, r0 = blockIdx.y * 32;
#pragma unroll
  for (int yy = threadIdx.y; yy < 32; yy += 8)
    tile[yy][threadIdx.x] = in[(long)(r0 + yy) * 512 + c0 + threadIdx.x];
  __syncthreads();
#pragma unroll
  for (int yy = threadIdx.y; yy < 32; yy += 8) {
    const int e = c0 + yy;
    const int rowp = ((e >> 4) << 7) + h * 16 + (e & 15);
    out[(long)rowp * 512 + r0 + threadIdx.x] = f2bf(tile[threadIdx.x][yy]);
  }
}

// WoT2[h][f][e] = bf16(Wo[e*8+h][f])
__global__ void tcvt_wo2(const float* __restrict__ in, u16* __restrict__ out) {
  __shared__ float tile[32][33];
  const int h = blockIdx.z;
  const int e0 = blockIdx.x * 32, f0 = blockIdx.y * 32;
#pragma unroll
  for (int yy = threadIdx.y; yy < 32; yy += 8)
    tile[yy][threadIdx.x] = in[(long)((e0 + yy) * 8 + h) * 512 + f0 + threadIdx.x];
  __syncthreads();
#pragma unroll
  for (int yy = threadIdx.y; yy < 32; yy += 8)
    out[(long)h * 262144 + (long)(f0 + yy) * 512 + e0 + threadIdx.x] =
        f2bf(tile[threadIdx.x][yy]);
}

__global__ void reduce4_kernel(const float* __restrict__ p, const float* __restrict__ bo,
                               float* __restrict__ out)
{
  const long S = 8192L * 512;
  const long i4 = ((long)blockIdx.x * 256 + threadIdx.x) * 4;
  float4 a = *(const float4*)(p + i4);
  float4 b = *(const float4*)(p + S + i4);
  float4 c = *(const float4*)(p + 2 * S + i4);
  float4 d = *(const float4*)(p + 3 * S + i4);
  float4 bb = *(const float4*)(bo + (i4 & 511));
  float4 r;
  r.x = a.x + b.x + c.x + d.x + bb.x;
  r.y = a.y + b.y + c.y + d.y + bb.y;
  r.z = a.z + b.z + c.z + d.z + bb.z;
  r.w = a.w + b.w + c.w + d.w + bb.w;
  *(float4*)(out + i4) = r;
}

__global__ void reduce2c_kernel(const float* __restrict__ p, u16* __restrict__ out)
{
  const long S = 32L * 262144;
  const long i = ((long)blockIdx.x * 256 + threadIdx.x) * 8;
  float4 a0 = *(const float4*)(p + i);
  float4 a1 = *(const float4*)(p + i + 4);
  float4 b0 = *(const float4*)(p + S + i);
  float4 b1 = *(const float4*)(p + S + i + 4);
  u16 t[8] = {f2bf(a0.x + b0.x), f2bf(a0.y + b0.y), f2bf(a0.z + b0.z), f2bf(a0.w + b0.w),
              f2bf(a1.x + b1.x), f2bf(a1.y + b1.y), f2bf(a1.z + b1.z), f2bf(a1.w + b1.w)};
  uint4 w; __builtin_memcpy(&w, t, 16);
  *(uint4*)(out + i) = w;
}

extern "C" void kernel_launch(void* const* d_in, const int* in_sizes, int n_in,
                              void* d_out, int out_size, void* d_ws, size_t ws_size,
                              hipStream_t stream) {
  const float* q  = (const float*)d_in[0];
  const float* k  = (const float*)d_in[1];
  const float* v  = (const float*)d_in[2];
  const float* Wq = (const float*)d_in[3];
  const float* bq = (const float*)d_in[4];
  const float* Wk = (const float*)d_in[5];
  const float* bk = (const float*)d_in[6];
  const float* Wv = (const float*)d_in[7];
  const float* bv = (const float*)d_in[8];
  const float* Wo = (const float*)d_in[9];
  const float* bo = (const float*)d_in[10];
  float* outp = (float*)d_out;

  char* ws = (char*)d_ws;
  // layout (peak 212 MiB), liveness verified per stage:
  u16* qs    = (u16*)(ws);                  //   0- 64 qsP; live to final
  u16* ksT   = (u16*)(ws + (64L  << 20));   //  64-128 [b,h,e,s]; dead after ctx
  u16* W2Pt  = (u16*)(ws + (64L  << 20));   //  64- 80 after ctx (ksT dead)
  u16* vsT   = (u16*)(ws + (128L << 20));   // 128-192 [b,h,e,s]; written launch B
  u16* qb    = (u16*)(ws + (128L << 20));   // 128-136 inside vsT; dead after launch A
  u16* kb    = (u16*)(ws + (136L << 20));   // 136-144 inside vsT; dead after launch A
  u16* WqT   = (u16*)(ws + (144L << 20));   // 144-148 inside vsT; dead after launch A
  u16* WkT   = (u16*)(ws + (148L << 20));   // 148-152 inside vsT; dead after launch A
  float* Pf  = (float*)(ws + (128L << 20)); // 128-192 final partials (vsT dead)
  u16* vb    = (u16*)(ws + (192L << 20));   // 192-200; dead after launch B
  u16* WvT   = (u16*)(ws + (200L << 20));   // 200-204; dead after launch B
  u16* ctxT  = (u16*)(ws + (192L << 20));   // 192-208 ctx (vb/WvT dead)
  u16* WoT2  = (u16*)(ws + (208L << 20));   // 208-212 [h][f][e]
  float* Pfc = (float*)(ws + (212L << 20)); // 212-276 ctx partials (guarded)
  const bool ctx_split = ws_size >= (286L << 20);

  cvt3_kernel<<<6144, 256, 0, stream>>>(q, k, v, qb, kb, vb);

  dim3 tb(32, 8, 1);
  tcvt3_kernel<<<dim3(16, 16, 24), tb, 0, stream>>>(Wq, Wk, Wv, WqT, WkT, WvT);
  tcvt_wo2<<<dim3(16, 16, 8), tb, 0, stream>>>(Wo, WoT2);

  // launch A: Q + K merged (zsel 0,1); launch B: V (zsel 2)
  proj3_kernel<<<4096, 256, 0, stream>>>(qb, kb, vb, WqT, WkT, WvT,
                                         bq, bk, bv, qs, ksT, vsT, 0);
  proj3_kernel<<<2048, 256, 0, stream>>>(qb, kb, vb, WqT, WkT, WvT,
                                         bq, bk, bv, qs, ksT, vsT, 2);

  // ctx[b,h][d][e] = sum_s ksT[d][s]*vsT[e][s]
  if (ctx_split) {
    gemm_kernel<M_CTXS><<<1024, 256, 0, stream>>>(
        ksT, 0, 2048, vsT, 0, 2048, Pfc, 0, 512, 4, 4, 1024);
    reduce2c_kernel<<<4096, 256, 0, stream>>>(Pfc, ctxT);
  } else {
    gemm_kernel<M_PLAIN><<<512, 256, 0, stream>>>(
        ksT, 1048576, 2048, vsT, 1048576, 2048, ctxT, 262144, 512, 4, 4, 2048);
  }

  // W2Pt[b][f][perm(h,d)] = sum_e ctx[b,h][d][e]*WoT2[h][f][e]
  gemm_kernel<M_W2><<<512, 256, 0, stream>>>(
      ctxT, 262144, 512, WoT2, 0, 512, W2Pt, 0, 0, 4, 4, 512);

  // final partials: K=4096 split 4x1024
  gemm_kernel<M_FINAL><<<1024, 256, 0, stream>>>(
      qs, 0, 4096, W2Pt, 0, 4096, Pf, 0, 512, 4, 16, 1024);

  reduce4_kernel<<<4096, 256, 0, stream>>>(Pf, bo, outp);
}

// Round 16
// 290.176 us; speedup vs baseline: 1.2376x; 1.0741x over previous
//
#include <hip/hip_runtime.h>
#include <hip/hip_bf16.h>

typedef unsigned short u16;
typedef __bf16 bf16x8_t __attribute__((ext_vector_type(8)));
typedef float f32x4_t __attribute__((ext_vector_type(4)));

struct alignas(8) us4 { u16 v[4]; };

__device__ __forceinline__ u16 f2bf(float f) {
  __hip_bfloat16 h = __float2bfloat16(f);
  u16 u; __builtin_memcpy(&u, &h, 2); return u;
}

__device__ __forceinline__ void gload16(const u16* g, u16* l) {
  __builtin_amdgcn_global_load_lds(
      (const __attribute__((address_space(1))) void*)g,
      (__attribute__((address_space(3))) void*)l, 16, 0, 0);
}

#define BAR()  __builtin_amdgcn_s_barrier()
#define VMC(n) asm volatile("s_waitcnt vmcnt(%0)" :: "i"(n) : "memory")

// ============ projection kernel (zsel picks q/k/v) ============
// launch A: grid 4096, zoff 0 -> zsel {0,1} (Q,K).  launch B: grid 2048,
// zoff 2 -> zsel 2 (V).  128x128 tile, BK=32, 3-buf depth-2 counted-vmcnt
// loop (r9/r13-proven: 48KB LDS -> 3 blocks/CU), chunk-XOR swizzled LDS
// both-sides. Weights pre-interleaved (col n -> h=(n>>4)&7, e=(n>>7)*16+(n&15)).
// zsel 0: softmax + qsP[b][s][n]. zsel 1: softmax + [b,h,e,s].
// zsel 2: bias only + [b,h,e,s].
// ALIASING CONTRACT (launch-order dependent): launch A reads qb/kb/W{q,k}T at
// 128-152 MiB and writes 0-128; launch B writes vsT 128-192 (A's inputs dead).
__global__ __launch_bounds__(256, 2)
void proj3_kernel(const u16* __restrict__ qb, const u16* __restrict__ kb,
                  const u16* __restrict__ vb, const u16* __restrict__ WqT,
                  const u16* __restrict__ WkT, const u16* __restrict__ WvT,
                  const float* __restrict__ bq, const float* __restrict__ bk,
                  const float* __restrict__ bv, u16* __restrict__ qs,
                  u16* __restrict__ ksT, u16* __restrict__ vsT, int zoff)
{
  __shared__ __align__(16) u16 smem[24576];

  const int bid = blockIdx.x;
  const int chunk = gridDim.x >> 3;
  const int wg = (bid & 7) * chunk + (bid >> 3);   // XCD-bijective (grid % 8 == 0)
  const int zsel = zoff + (wg >> 11);
  const int rem = wg & 2047;
  const int by = rem >> 5;
  const int bx = rem & 31;

  const int tid = threadIdx.x;
  const int lane = tid & 63;
  const int wave = tid >> 6;
  const int wm = (wave >> 1) * 64;
  const int wn = (wave & 1) * 64;
  const int m0 = by * 128;

  const u16* Az = zsel == 0 ? qb : (zsel == 1 ? kb : vb);
  const u16* Bz = zsel == 0 ? WqT : (zsel == 1 ? WkT : WvT);
  const float* bias = zsel == 0 ? bq : (zsel == 1 ? bk : bv);
  u16* outp = zsel == 0 ? qs : (zsel == 1 ? ksT : vsT);
  const bool doSM = (zsel < 2);

  const int srow = tid >> 2;
  const int scol = (((tid & 3) ^ ((tid >> 3) & 3)) << 3);
  const u16* aptr0 = Az + (long)(m0 + srow) * 512 + scol;
  const u16* aptr1 = aptr0 + (long)64 * 512;
  const u16* bptr0 = Bz + (long)(bx * 128 + srow) * 512 + scol;
  const u16* bptr1 = bptr0 + (long)64 * 512;

  f32x4_t acc[4][4];
#pragma unroll
  for (int i = 0; i < 4; i++)
#pragma unroll
    for (int j = 0; j < 4; j++) acc[i][j] = (f32x4_t){0.f, 0.f, 0.f, 0.f};

  const int kg = lane >> 4;
  const int fr = lane & 15;

  int aoffL[4], boffL[4];
#pragma unroll
  for (int i = 0; i < 4; i++) {
    const int r = wm + i * 16 + fr;
    aoffL[i] = r * 32 + ((kg ^ ((r >> 1) & 3)) << 3);
  }
#pragma unroll
  for (int j = 0; j < 4; j++) {
    const int r = wn + j * 16 + fr;
    boffL[j] = 4096 + r * 32 + ((kg ^ ((r >> 1) & 3)) << 3);
  }

  auto stage = [&](int t, u16* nb) {
    const int ko = t * 32;
    gload16(aptr0 + ko, nb + tid * 8);
    gload16(aptr1 + ko, nb + (tid + 256) * 8);
    gload16(bptr0 + ko, nb + 4096 + tid * 8);
    gload16(bptr1 + ko, nb + 4096 + (tid + 256) * 8);
  };

  stage(0, smem);
  stage(1, smem + 8192);

  for (int t = 0; t < 16; t++) {
    if (t < 15) VMC(4);
    else        VMC(0);
    BAR();
    asm volatile("" ::: "memory");
    if (t + 2 < 16) stage(t + 2, smem + ((t + 2) % 3) * 8192);
    const u16* cb = smem + (t % 3) * 8192;
    bf16x8_t afr[4], bfr[4];
#pragma unroll
    for (int i = 0; i < 4; i++) afr[i] = *(const bf16x8_t*)&cb[aoffL[i]];
#pragma unroll
    for (int j = 0; j < 4; j++) bfr[j] = *(const bf16x8_t*)&cb[boffL[j]];
#pragma unroll
    for (int i = 0; i < 4; i++)
#pragma unroll
      for (int j = 0; j < 4; j++)
        acc[i][j] = __builtin_amdgcn_mfma_f32_16x16x32_bf16(afr[i], bfr[j], acc[i][j], 0, 0, 0);
  }
  __syncthreads();  // full drain before smem reuse

  // ---- fused softmax over heads (zsel 0,1) ----
  if (doSM) {
    float* ex = (float*)smem;          // stride 17 -> conflict-free
    float* ex2 = ex + 4352;
    const int wmg = wave >> 1, wng = wave & 1;
    const int self = ((wmg * 2 + wng) * 64 + lane) * 17;
    const int part = ((wmg * 2 + (wng ^ 1)) * 64 + lane) * 17;
    float bj[4];
#pragma unroll
    for (int j = 0; j < 4; j++) bj[j] = bias[((wn >> 4) + j) * 512 + bx * 16 + fr];
#pragma unroll
    for (int i = 0; i < 4; i++)
#pragma unroll
      for (int j = 0; j < 4; j++)
#pragma unroll
        for (int r = 0; r < 4; r++) acc[i][j][r] += bj[j];
    float mx[16];
#pragma unroll
    for (int i = 0; i < 4; i++)
#pragma unroll
      for (int r = 0; r < 4; r++) {
        float m = acc[i][0][r];
#pragma unroll
        for (int j = 1; j < 4; j++) m = fmaxf(m, acc[i][j][r]);
        mx[i * 4 + r] = m;
      }
#pragma unroll
    for (int t = 0; t < 16; t++) ex[self + t] = mx[t];
    __syncthreads();
#pragma unroll
    for (int t = 0; t < 16; t++) mx[t] = fmaxf(mx[t], ex[part + t]);
    float sm[16];
#pragma unroll
    for (int t = 0; t < 16; t++) sm[t] = 0.f;
#pragma unroll
    for (int i = 0; i < 4; i++)
#pragma unroll
      for (int j = 0; j < 4; j++)
#pragma unroll
        for (int r = 0; r < 4; r++) {
          float p = __expf(acc[i][j][r] - mx[i * 4 + r]);
          acc[i][j][r] = p;
          sm[i * 4 + r] += p;
        }
#pragma unroll
    for (int t = 0; t < 16; t++) ex2[self + t] = sm[t];
    __syncthreads();
#pragma unroll
    for (int t = 0; t < 16; t++) sm[t] = 1.f / (sm[t] + ex2[part + t]);
#pragma unroll
    for (int i = 0; i < 4; i++)
#pragma unroll
      for (int j = 0; j < 4; j++)
#pragma unroll
        for (int r = 0; r < 4; r++) acc[i][j][r] *= sm[i * 4 + r];
    __syncthreads();
  }

  // ---- LDS-staged epilogue: Cs[128][136] ----
  constexpr int CW = 136;
  u16* Cs = smem;
  const int b = m0 >> 11, s0 = m0 & 2047;
  if (zsel == 0) {
    // qsP[b][s][bx*128 + c]
#pragma unroll
    for (int j = 0; j < 4; j++) {
      const int c = wn + j * 16 + fr;
#pragma unroll
      for (int i = 0; i < 4; i++) {
        const int rbase = wm + i * 16 + ((lane >> 4) << 2);
#pragma unroll
        for (int r = 0; r < 4; r++)
          Cs[(rbase + r) * CW + c] = f2bf(acc[i][j][r]);
      }
    }
    __syncthreads();
    const long base = (long)b * 8388608 + (long)s0 * 4096 + bx * 128;
#pragma unroll
    for (int it = 0; it < 8; it++) {
      const int idx = it * 256 + tid;
      const int row = idx >> 4, ch = idx & 15;
      *(uint4*)&outp[base + (long)row * 4096 + ch * 8] = *(const uint4*)&Cs[row * CW + ch * 8];
    }
  } else {
    // transposed tile: Cs[row = tile col c][col = s]; bias only for v (zsel 2)
#pragma unroll
    for (int j = 0; j < 4; j++) {
      const int c = wn + j * 16 + fr;
      const float bb = doSM ? 0.f : bias[((wn >> 4) + j) * 512 + bx * 16 + fr];
#pragma unroll
      for (int i = 0; i < 4; i++) {
        us4 w;
#pragma unroll
        for (int r = 0; r < 4; r++) w.v[r] = f2bf(acc[i][j][r] + bb);
        *(us4*)&Cs[c * CW + wm + i * 16 + ((lane >> 4) << 2)] = w;
      }
    }
    __syncthreads();
#pragma unroll
    for (int it = 0; it < 8; it++) {
      const int idx = it * 256 + tid;
      const int row = idx >> 4, ch = idx & 15;
      const long base = (long)(b * 8 + (row >> 4)) * 1048576 +
                        (long)(bx * 16 + (row & 15)) * 2048 + s0;
      *(uint4*)&outp[base + ch * 8] = *(const uint4*)&Cs[row * CW + ch * 8];
    }
  }
}

// ================= r9 128x128 core for ctx / W2 / final =================
#define M_PLAIN 2
#define M_W2    3
#define M_FINAL 4
#define M_CTXS  5

template<int MODE>
__global__ __launch_bounds__(256, 2)
void gemm_kernel(const u16* __restrict__ A, long sAz, int lda,
                 const u16* __restrict__ B, long sBz, int ldb,
                 void* __restrict__ Cv, long sCz, int ldc,
                 int nx, int ny, int K)
{
  __shared__ __align__(16) u16 smem[24576];

  const int nwg = gridDim.x;
  const int chunk = nwg >> 3;
  const int bid = blockIdx.x;
  const int wg = (bid & 7) * chunk + (bid >> 3);
  const int nxy = nx * ny;
  const int z = wg / nxy;
  const int rem = wg - z * nxy;
  const int by = rem / nx;
  const int bx = rem - by * nx;

  const int tid = threadIdx.x;
  const int lane = tid & 63;
  const int wave = tid >> 6;
  const int wm = (wave >> 1) * 64;
  const int wn = (wave & 1) * 64;
  const int m0 = by * 128;
  const int n0 = bx * 128;

  const u16* Az; const u16* Bz;
  if constexpr (MODE == M_CTXS) {
    const int bh = z & 31, kc = z >> 5;
    Az = A + (long)bh * 1048576 + kc * 1024;
    Bz = B + (long)bh * 1048576 + kc * 1024;
  } else if constexpr (MODE == M_W2) {
    Az = A + (long)z * 262144;
    Bz = B + (long)(z & 7) * 262144;
  } else if constexpr (MODE == M_FINAL) {
    Az = A + (long)(z >> 2) * 8388608 + (z & 3) * 1024;
    Bz = B + (long)(z >> 2) * 2097152 + (z & 3) * 1024;
  } else {
    Az = A + (long)z * sAz;
    Bz = B + (long)z * sBz;
  }

  const int srow = tid >> 2;
  const int scol = (((tid & 3) ^ ((tid >> 3) & 3)) << 3);
  const u16* aptr0 = Az + (long)(m0 + srow) * lda + scol;
  const u16* aptr1 = aptr0 + (long)64 * lda;
  const u16* bptr0 = Bz + (long)(n0 + srow) * ldb + scol;
  const u16* bptr1 = bptr0 + (long)64 * ldb;

  f32x4_t acc[4][4];
#pragma unroll
  for (int i = 0; i < 4; i++)
#pragma unroll
    for (int j = 0; j < 4; j++) acc[i][j] = (f32x4_t){0.f, 0.f, 0.f, 0.f};

  const int kg = lane >> 4;
  const int fr = lane & 15;
  const int nt = K >> 5;

  int aoffL[4], boffL[4];
#pragma unroll
  for (int i = 0; i < 4; i++) {
    const int r = wm + i * 16 + fr;
    aoffL[i] = r * 32 + ((kg ^ ((r >> 1) & 3)) << 3);
  }
#pragma unroll
  for (int j = 0; j < 4; j++) {
    const int r = wn + j * 16 + fr;
    boffL[j] = 4096 + r * 32 + ((kg ^ ((r >> 1) & 3)) << 3);
  }

  auto stage = [&](int t, u16* nb) {
    const int ko = t * 32;
    gload16(aptr0 + ko, nb + tid * 8);
    gload16(aptr1 + ko, nb + (tid + 256) * 8);
    gload16(bptr0 + ko, nb + 4096 + tid * 8);
    gload16(bptr1 + ko, nb + 4096 + (tid + 256) * 8);
  };

  stage(0, smem);
  stage(1, smem + 8192);

  for (int t = 0; t < nt; t++) {
    if (t < nt - 1) VMC(4);
    else            VMC(0);
    BAR();
    asm volatile("" ::: "memory");
    if (t + 2 < nt) stage(t + 2, smem + ((t + 2) % 3) * 8192);
    const u16* cb = smem + (t % 3) * 8192;
    bf16x8_t afr[4], bfr[4];
#pragma unroll
    for (int i = 0; i < 4; i++) afr[i] = *(const bf16x8_t*)&cb[aoffL[i]];
#pragma unroll
    for (int j = 0; j < 4; j++) bfr[j] = *(const bf16x8_t*)&cb[boffL[j]];
#pragma unroll
    for (int i = 0; i < 4; i++)
#pragma unroll
      for (int j = 0; j < 4; j++)
        acc[i][j] = __builtin_amdgcn_mfma_f32_16x16x32_bf16(afr[i], bfr[j], acc[i][j], 0, 0, 0);
  }
  __syncthreads();

  if constexpr (MODE == M_FINAL || MODE == M_CTXS) {
    float* o;
    if constexpr (MODE == M_FINAL)
      o = (float*)Cv + (long)(z & 3) * 4194304 + (long)(z >> 2) * 1048576;
    else
      o = (float*)Cv + (long)z * 262144;
#pragma unroll
    for (int i = 0; i < 4; i++) {
      const int rbase = m0 + wm + i * 16 + ((lane >> 4) << 2);
#pragma unroll
      for (int j = 0; j < 4; j++) {
        const int gc = n0 + wn + j * 16 + fr;
#pragma unroll
        for (int r = 0; r < 4; r++)
          o[(long)(rbase + r) * ldc + gc] = acc[i][j][r];
      }
    }
    return;
  }

  constexpr int CW = 136;
  u16* Cs = smem;
  if constexpr (MODE == M_W2) {
#pragma unroll
    for (int j = 0; j < 4; j++) {
      const int c = wn + j * 16 + fr;
#pragma unroll
      for (int i = 0; i < 4; i++) {
        us4 w;
#pragma unroll
        for (int r = 0; r < 4; r++) w.v[r] = f2bf(acc[i][j][r]);
        *(us4*)&Cs[c * CW + wm + i * 16 + ((lane >> 4) << 2)] = w;
      }
    }
  } else {
#pragma unroll
    for (int j = 0; j < 4; j++) {
      const int c = wn + j * 16 + fr;
#pragma unroll
      for (int i = 0; i < 4; i++) {
        const int rbase = wm + i * 16 + ((lane >> 4) << 2);
#pragma unroll
        for (int r = 0; r < 4; r++)
          Cs[(rbase + r) * CW + c] = f2bf(acc[i][j][r]);
      }
    }
  }
  __syncthreads();

  u16* dst = (u16*)Cv;
  if constexpr (MODE == M_W2) {
    const int b = z >> 3, h = z & 7;
    const long base0 = (long)b * 2097152 + (long)n0 * 4096 + ((m0 >> 4) << 7) + h * 16;
#pragma unroll
    for (int it = 0; it < 4; it++) {
      const int idx = it * 256 + tid;
      const int row = idx >> 3, ch = idx & 7;
      const long base = base0 + (long)row * 4096 + ch * 128;
      *(uint4*)&dst[base] = *(const uint4*)&Cs[row * CW + ch * 16];
      *(uint4*)&dst[base + 8] = *(const uint4*)&Cs[row * CW + ch * 16 + 8];
    }
  } else {  // M_PLAIN
    const long base = (long)z * sCz + (long)m0 * ldc + n0;
#pragma unroll
    for (int it = 0; it < 8; it++) {
      const int idx = it * 256 + tid;
      const int row = idx >> 4, ch = idx & 15;
      *(uint4*)&dst[base + (long)row * ldc + ch * 8] = *(const uint4*)&Cs[row * CW + ch * 8];
    }
  }
}

// ---------------- support kernels ----------------
__global__ void cvt3_kernel(const float* __restrict__ q, const float* __restrict__ k,
                            const float* __restrict__ v, u16* __restrict__ qb,
                            u16* __restrict__ kb, u16* __restrict__ vb) {
  const int arr = blockIdx.x >> 11;
  const int lb = blockIdx.x & 2047;
  const float* in = arr == 0 ? q : (arr == 1 ? k : v);
  u16* out = arr == 0 ? qb : (arr == 1 ? kb : vb);
  const long i = ((long)lb * 256 + threadIdx.x) * 8;
  float4 a = *(const float4*)(in + i);
  float4 b = *(const float4*)(in + i + 4);
  u16 t[8] = {f2bf(a.x), f2bf(a.y), f2bf(a.z), f2bf(a.w),
              f2bf(b.x), f2bf(b.y), f2bf(b.z), f2bf(b.w)};
  uint4 w; __builtin_memcpy(&w, t, 16);
  *(uint4*)(out + i) = w;
}

// WT[(e>>4)*128 + h*16 + (e&15)][d] = bf16(W[h][d][e])
__global__ void tcvt3_kernel(const float* __restrict__ Wq, const float* __restrict__ Wk,
                             const float* __restrict__ Wv, u16* __restrict__ WqT,
                             u16* __restrict__ WkT, u16* __restrict__ WvT)
{
  __shared__ float tile[32][33];
  const int arr = blockIdx.z >> 3;
  const int h = blockIdx.z & 7;
  const float* in = (arr == 0 ? Wq : (arr == 1 ? Wk : Wv)) + (long)h * 262144;
  u16* out = arr == 0 ? WqT : (arr == 1 ? WkT : WvT);
  const int c0 = blockIdx.x * 32, r0 = blockIdx.y * 32;
#pragma unroll
  for (int yy = threadIdx.y; yy < 32; yy += 8)
    tile[yy][threadIdx.x] = in[(long)(r0 + yy) * 512 + c0 + threadIdx.x];
  __syncthreads();
#pragma unroll
  for (int yy = threadIdx.y; yy < 32; yy += 8) {
    const int e = c0 + yy;
    const int rowp = ((e >> 4) << 7) + h * 16 + (e & 15);
    out[(long)rowp * 512 + r0 + threadIdx.x] = f2bf(tile[threadIdx.x][yy]);
  }
}

// WoT2[h][f][e] = bf16(Wo[e*8+h][f])
__global__ void tcvt_wo2(const float* __restrict__ in, u16* __restrict__ out) {
  __shared__ float tile[32][33];
  const int h = blockIdx.z;
  const int e0 = blockIdx.x * 32, f0 = blockIdx.y * 32;
#pragma unroll
  for (int yy = threadIdx.y; yy < 32; yy += 8)
    tile[yy][threadIdx.x] = in[(long)((e0 + yy) * 8 + h) * 512 + f0 + threadIdx.x];
  __syncthreads();
#pragma unroll
  for (int yy = threadIdx.y; yy < 32; yy += 8)
    out[(long)h * 262144 + (long)(f0 + yy) * 512 + e0 + threadIdx.x] =
        f2bf(tile[threadIdx.x][yy]);
}

__global__ void reduce4_kernel(const float* __restrict__ p, const float* __restrict__ bo,
                               float* __restrict__ out)
{
  const long S = 8192L * 512;
  const long i4 = ((long)blockIdx.x * 256 + threadIdx.x) * 4;
  float4 a = *(const float4*)(p + i4);
  float4 b = *(const float4*)(p + S + i4);
  float4 c = *(const float4*)(p + 2 * S + i4);
  float4 d = *(const float4*)(p + 3 * S + i4);
  float4 bb = *(const float4*)(bo + (i4 & 511));
  float4 r;
  r.x = a.x + b.x + c.x + d.x + bb.x;
  r.y = a.y + b.y + c.y + d.y + bb.y;
  r.z = a.z + b.z + c.z + d.z + bb.z;
  r.w = a.w + b.w + c.w + d.w + bb.w;
  *(float4*)(out + i4) = r;
}

__global__ void reduce2c_kernel(const float* __restrict__ p, u16* __restrict__ out)
{
  const long S = 32L * 262144;
  const long i = ((long)blockIdx.x * 256 + threadIdx.x) * 8;
  float4 a0 = *(const float4*)(p + i);
  float4 a1 = *(const float4*)(p + i + 4);
  float4 b0 = *(const float4*)(p + S + i);
  float4 b1 = *(const float4*)(p + S + i + 4);
  u16 t[8] = {f2bf(a0.x + b0.x), f2bf(a0.y + b0.y), f2bf(a0.z + b0.z), f2bf(a0.w + b0.w),
              f2bf(a1.x + b1.x), f2bf(a1.y + b1.y), f2bf(a1.z + b1.z), f2bf(a1.w + b1.w)};
  uint4 w; __builtin_memcpy(&w, t, 16);
  *(uint4*)(out + i) = w;
}

extern "C" void kernel_launch(void* const* d_in, const int* in_sizes, int n_in,
                              void* d_out, int out_size, void* d_ws, size_t ws_size,
                              hipStream_t stream) {
  const float* q  = (const float*)d_in[0];
  const float* k  = (const float*)d_in[1];
  const float* v  = (const float*)d_in[2];
  const float* Wq = (const float*)d_in[3];
  const float* bq = (const float*)d_in[4];
  const float* Wk = (const float*)d_in[5];
  const float* bk = (const float*)d_in[6];
  const float* Wv = (const float*)d_in[7];
  const float* bv = (const float*)d_in[8];
  const float* Wo = (const float*)d_in[9];
  const float* bo = (const float*)d_in[10];
  float* outp = (float*)d_out;

  char* ws = (char*)d_ws;
  // layout (peak 212 MiB), liveness verified per stage:
  u16* qs    = (u16*)(ws);                  //   0- 64 qsP; live to final
  u16* ksT   = (u16*)(ws + (64L  << 20));   //  64-128 [b,h,e,s]; dead after ctx
  u16* W2Pt  = (u16*)(ws + (64L  << 20));   //  64- 80 after ctx (ksT dead)
  u16* vsT   = (u16*)(ws + (128L << 20));   // 128-192 [b,h,e,s]; written launch B
  u16* qb    = (u16*)(ws + (128L << 20));   // 128-136 inside vsT; dead after launch A
  u16* kb    = (u16*)(ws + (136L << 20));   // 136-144 inside vsT; dead after launch A
  u16* WqT   = (u16*)(ws + (144L << 20));   // 144-148 inside vsT; dead after launch A
  u16* WkT   = (u16*)(ws + (148L << 20));   // 148-152 inside vsT; dead after launch A
  float* Pf  = (float*)(ws + (128L << 20)); // 128-192 final partials (vsT dead)
  u16* vb    = (u16*)(ws + (192L << 20));   // 192-200; dead after launch B
  u16* WvT   = (u16*)(ws + (200L << 20));   // 200-204; dead after launch B
  u16* ctxT  = (u16*)(ws + (192L << 20));   // 192-208 ctx (vb/WvT dead)
  u16* WoT2  = (u16*)(ws + (208L << 20));   // 208-212 [h][f][e]
  float* Pfc = (float*)(ws + (212L << 20)); // 212-276 ctx partials (guarded)
  const bool ctx_split = ws_size >= (286L << 20);

  cvt3_kernel<<<6144, 256, 0, stream>>>(q, k, v, qb, kb, vb);

  dim3 tb(32, 8, 1);
  tcvt3_kernel<<<dim3(16, 16, 24), tb, 0, stream>>>(Wq, Wk, Wv, WqT, WkT, WvT);
  tcvt_wo2<<<dim3(16, 16, 8), tb, 0, stream>>>(Wo, WoT2);

  // launch A: Q + K merged (zsel 0,1); launch B: V (zsel 2)
  proj3_kernel<<<4096, 256, 0, stream>>>(qb, kb, vb, WqT, WkT, WvT,
                                         bq, bk, bv, qs, ksT, vsT, 0);
  proj3_kernel<<<2048, 256, 0, stream>>>(qb, kb, vb, WqT, WkT, WvT,
                                         bq, bk, bv, qs, ksT, vsT, 2);

  // ctx[b,h][d][e] = sum_s ksT[d][s]*vsT[e][s]
  if (ctx_split) {
    gemm_kernel<M_CTXS><<<1024, 256, 0, stream>>>(
        ksT, 0, 2048, vsT, 0, 2048, Pfc, 0, 512, 4, 4, 1024);
    reduce2c_kernel<<<4096, 256, 0, stream>>>(Pfc, ctxT);
  } else {
    gemm_kernel<M_PLAIN><<<512, 256, 0, stream>>>(
        ksT, 1048576, 2048, vsT, 1048576, 2048, ctxT, 262144, 512, 4, 4, 2048);
  }

  // W2Pt[b][f][perm(h,d)] = sum_e ctx[b,h][d][e]*WoT2[h][f][e]
  gemm_kernel<M_W2><<<512, 256, 0, stream>>>(
      ctxT, 262144, 512, WoT2, 0, 512, W2Pt, 0, 0, 4, 4, 512);

  // final partials: K=4096 split 4x1024
  gemm_kernel<M_FINAL><<<1024, 256, 0, stream>>>(
      qs, 0, 4096, W2Pt, 0, 4096, Pf, 0, 512, 4, 16, 1024);

  reduce4_kernel<<<4096, 256, 0, stream>>>(Pf, bo, outp);
}

// Round 17
// 276.200 us; speedup vs baseline: 1.3002x; 1.0506x over previous
//
#include <hip/hip_runtime.h>
#include <hip/hip_bf16.h>

typedef unsigned short u16;
typedef __bf16 bf16x8_t __attribute__((ext_vector_type(8)));
typedef float f32x4_t __attribute__((ext_vector_type(4)));

struct alignas(8) us4 { u16 v[4]; };

__device__ __forceinline__ u16 f2bf(float f) {
  __hip_bfloat16 h = __float2bfloat16(f);
  u16 u; __builtin_memcpy(&u, &h, 2); return u;
}

__device__ __forceinline__ void gload16(const u16* g, u16* l) {
  __builtin_amdgcn_global_load_lds(
      (const __attribute__((address_space(1))) void*)g,
      (__attribute__((address_space(3))) void*)l, 16, 0, 0);
}

#define BAR()  __builtin_amdgcn_s_barrier()
#define VMC(n) asm volatile("s_waitcnt vmcnt(%0)" :: "i"(n) : "memory")

// ============ projection kernel (zsel picks q/k/v) ============
// launch A: grid 4096, zoff 0 -> zsel {0,1} (Q,K).  launch B: grid 2048,
// zoff 2 -> zsel 2 (V).  128x128 tile, BK=32, 3-buf depth-2 counted-vmcnt
// loop (r13-proven: 48KB LDS -> 3 blocks/CU), chunk-XOR swizzled LDS
// both-sides. Weights pre-interleaved (col n -> h=(n>>4)&7, e=(n>>7)*16+(n&15)).
// NEW (r17): 8x8 supertile block ordering — 64 consecutive wg share 8 A-panels
// + 8 B-panels (2 MB) so an XCD's concurrent blocks L2-hit their loads.
// zsel 0: softmax + qsP[b][s][n]. zsel 1: softmax + [b,h,e,s].
// zsel 2: bias only + [b,h,e,s].
// ALIASING CONTRACT (launch-order dependent): launch A reads qb/kb/W{q,k}T at
// 128-152 MiB and writes 0-128; launch B writes vsT 128-192 (A's inputs dead).
__global__ __launch_bounds__(256, 2)
void proj3_kernel(const u16* __restrict__ qb, const u16* __restrict__ kb,
                  const u16* __restrict__ vb, const u16* __restrict__ WqT,
                  const u16* __restrict__ WkT, const u16* __restrict__ WvT,
                  const float* __restrict__ bq, const float* __restrict__ bk,
                  const float* __restrict__ bv, u16* __restrict__ qs,
                  u16* __restrict__ ksT, u16* __restrict__ vsT, int zoff)
{
  __shared__ __align__(16) u16 smem[24576];

  const int bid = blockIdx.x;
  const int chunk = gridDim.x >> 3;
  const int wg = (bid & 7) * chunk + (bid >> 3);   // XCD-bijective (grid % 8 == 0)
  const int zsel = zoff + (wg >> 11);
  const int rem = wg & 2047;
  // supertile remap: st = 8 by-groups x 4 bx-groups; inner = 8x8 blocks
  const int st = rem >> 6;          // 0..31
  const int inner = rem & 63;       // 0..63
  const int by = ((st >> 2) << 3) + (inner >> 3);  // 0..63
  const int bx = ((st & 3) << 3) + (inner & 7);    // 0..31

  const int tid = threadIdx.x;
  const int lane = tid & 63;
  const int wave = tid >> 6;
  const int wm = (wave >> 1) * 64;
  const int wn = (wave & 1) * 64;
  const int m0 = by * 128;

  const u16* Az = zsel == 0 ? qb : (zsel == 1 ? kb : vb);
  const u16* Bz = zsel == 0 ? WqT : (zsel == 1 ? WkT : WvT);
  const float* bias = zsel == 0 ? bq : (zsel == 1 ? bk : bv);
  u16* outp = zsel == 0 ? qs : (zsel == 1 ? ksT : vsT);
  const bool doSM = (zsel < 2);

  const int srow = tid >> 2;
  const int scol = (((tid & 3) ^ ((tid >> 3) & 3)) << 3);
  const u16* aptr0 = Az + (long)(m0 + srow) * 512 + scol;
  const u16* aptr1 = aptr0 + (long)64 * 512;
  const u16* bptr0 = Bz + (long)(bx * 128 + srow) * 512 + scol;
  const u16* bptr1 = bptr0 + (long)64 * 512;

  f32x4_t acc[4][4];
#pragma unroll
  for (int i = 0; i < 4; i++)
#pragma unroll
    for (int j = 0; j < 4; j++) acc[i][j] = (f32x4_t){0.f, 0.f, 0.f, 0.f};

  const int kg = lane >> 4;
  const int fr = lane & 15;

  int aoffL[4], boffL[4];
#pragma unroll
  for (int i = 0; i < 4; i++) {
    const int r = wm + i * 16 + fr;
    aoffL[i] = r * 32 + ((kg ^ ((r >> 1) & 3)) << 3);
  }
#pragma unroll
  for (int j = 0; j < 4; j++) {
    const int r = wn + j * 16 + fr;
    boffL[j] = 4096 + r * 32 + ((kg ^ ((r >> 1) & 3)) << 3);
  }

  auto stage = [&](int t, u16* nb) {
    const int ko = t * 32;
    gload16(aptr0 + ko, nb + tid * 8);
    gload16(aptr1 + ko, nb + (tid + 256) * 8);
    gload16(bptr0 + ko, nb + 4096 + tid * 8);
    gload16(bptr1 + ko, nb + 4096 + (tid + 256) * 8);
  };

  stage(0, smem);
  stage(1, smem + 8192);

  for (int t = 0; t < 16; t++) {
    if (t < 15) VMC(4);
    else        VMC(0);
    BAR();
    asm volatile("" ::: "memory");
    if (t + 2 < 16) stage(t + 2, smem + ((t + 2) % 3) * 8192);
    const u16* cb = smem + (t % 3) * 8192;
    bf16x8_t afr[4], bfr[4];
#pragma unroll
    for (int i = 0; i < 4; i++) afr[i] = *(const bf16x8_t*)&cb[aoffL[i]];
#pragma unroll
    for (int j = 0; j < 4; j++) bfr[j] = *(const bf16x8_t*)&cb[boffL[j]];
#pragma unroll
    for (int i = 0; i < 4; i++)
#pragma unroll
      for (int j = 0; j < 4; j++)
        acc[i][j] = __builtin_amdgcn_mfma_f32_16x16x32_bf16(afr[i], bfr[j], acc[i][j], 0, 0, 0);
  }
  __syncthreads();  // full drain before smem reuse

  // ---- fused softmax over heads (zsel 0,1) ----
  if (doSM) {
    float* ex = (float*)smem;          // stride 17 -> conflict-free
    float* ex2 = ex + 4352;
    const int wmg = wave >> 1, wng = wave & 1;
    const int self = ((wmg * 2 + wng) * 64 + lane) * 17;
    const int part = ((wmg * 2 + (wng ^ 1)) * 64 + lane) * 17;
    float bj[4];
#pragma unroll
    for (int j = 0; j < 4; j++) bj[j] = bias[((wn >> 4) + j) * 512 + bx * 16 + fr];
#pragma unroll
    for (int i = 0; i < 4; i++)
#pragma unroll
      for (int j = 0; j < 4; j++)
#pragma unroll
        for (int r = 0; r < 4; r++) acc[i][j][r] += bj[j];
    float mx[16];
#pragma unroll
    for (int i = 0; i < 4; i++)
#pragma unroll
      for (int r = 0; r < 4; r++) {
        float m = acc[i][0][r];
#pragma unroll
        for (int j = 1; j < 4; j++) m = fmaxf(m, acc[i][j][r]);
        mx[i * 4 + r] = m;
      }
#pragma unroll
    for (int t = 0; t < 16; t++) ex[self + t] = mx[t];
    __syncthreads();
#pragma unroll
    for (int t = 0; t < 16; t++) mx[t] = fmaxf(mx[t], ex[part + t]);
    float sm[16];
#pragma unroll
    for (int t = 0; t < 16; t++) sm[t] = 0.f;
#pragma unroll
    for (int i = 0; i < 4; i++)
#pragma unroll
      for (int j = 0; j < 4; j++)
#pragma unroll
        for (int r = 0; r < 4; r++) {
          float p = __expf(acc[i][j][r] - mx[i * 4 + r]);
          acc[i][j][r] = p;
          sm[i * 4 + r] += p;
        }
#pragma unroll
    for (int t = 0; t < 16; t++) ex2[self + t] = sm[t];
    __syncthreads();
#pragma unroll
    for (int t = 0; t < 16; t++) sm[t] = 1.f / (sm[t] + ex2[part + t]);
#pragma unroll
    for (int i = 0; i < 4; i++)
#pragma unroll
      for (int j = 0; j < 4; j++)
#pragma unroll
        for (int r = 0; r < 4; r++) acc[i][j][r] *= sm[i * 4 + r];
    __syncthreads();
  }

  // ---- LDS-staged epilogue: Cs[128][136] ----
  constexpr int CW = 136;
  u16* Cs = smem;
  const int b = m0 >> 11, s0 = m0 & 2047;
  if (zsel == 0) {
    // qsP[b][s][bx*128 + c]
#pragma unroll
    for (int j = 0; j < 4; j++) {
      const int c = wn + j * 16 + fr;
#pragma unroll
      for (int i = 0; i < 4; i++) {
        const int rbase = wm + i * 16 + ((lane >> 4) << 2);
#pragma unroll
        for (int r = 0; r < 4; r++)
          Cs[(rbase + r) * CW + c] = f2bf(acc[i][j][r]);
      }
    }
    __syncthreads();
    const long base = (long)b * 8388608 + (long)s0 * 4096 + bx * 128;
#pragma unroll
    for (int it = 0; it < 8; it++) {
      const int idx = it * 256 + tid;
      const int row = idx >> 4, ch = idx & 15;
      *(uint4*)&outp[base + (long)row * 4096 + ch * 8] = *(const uint4*)&Cs[row * CW + ch * 8];
    }
  } else {
    // transposed tile: Cs[row = tile col c][col = s]; bias only for v (zsel 2)
#pragma unroll
    for (int j = 0; j < 4; j++) {
      const int c = wn + j * 16 + fr;
      const float bb = doSM ? 0.f : bias[((wn >> 4) + j) * 512 + bx * 16 + fr];
#pragma unroll
      for (int i = 0; i < 4; i++) {
        us4 w;
#pragma unroll
        for (int r = 0; r < 4; r++) w.v[r] = f2bf(acc[i][j][r] + bb);
        *(us4*)&Cs[c * CW + wm + i * 16 + ((lane >> 4) << 2)] = w;
      }
    }
    __syncthreads();
#pragma unroll
    for (int it = 0; it < 8; it++) {
      const int idx = it * 256 + tid;
      const int row = idx >> 4, ch = idx & 15;
      const long base = (long)(b * 8 + (row >> 4)) * 1048576 +
                        (long)(bx * 16 + (row & 15)) * 2048 + s0;
      *(uint4*)&outp[base + ch * 8] = *(const uint4*)&Cs[row * CW + ch * 8];
    }
  }
}

// ================= r9 128x128 core for ctx / W2 / final =================
#define M_PLAIN 2
#define M_W2    3
#define M_FINAL 4
#define M_CTXS  5

template<int MODE>
__global__ __launch_bounds__(256, 2)
void gemm_kernel(const u16* __restrict__ A, long sAz, int lda,
                 const u16* __restrict__ B, long sBz, int ldb,
                 void* __restrict__ Cv, long sCz, int ldc,
                 int nx, int ny, int K)
{
  __shared__ __align__(16) u16 smem[24576];

  const int nwg = gridDim.x;
  const int chunk = nwg >> 3;
  const int bid = blockIdx.x;
  const int wg = (bid & 7) * chunk + (bid >> 3);
  const int nxy = nx * ny;
  const int z = wg / nxy;
  const int rem = wg - z * nxy;
  const int by = rem / nx;
  const int bx = rem - by * nx;

  const int tid = threadIdx.x;
  const int lane = tid & 63;
  const int wave = tid >> 6;
  const int wm = (wave >> 1) * 64;
  const int wn = (wave & 1) * 64;
  const int m0 = by * 128;
  const int n0 = bx * 128;

  const u16* Az; const u16* Bz;
  if constexpr (MODE == M_CTXS) {
    const int bh = z & 31, kc = z >> 5;
    Az = A + (long)bh * 1048576 + kc * 1024;
    Bz = B + (long)bh * 1048576 + kc * 1024;
  } else if constexpr (MODE == M_W2) {
    Az = A + (long)z * 262144;
    Bz = B + (long)(z & 7) * 262144;
  } else if constexpr (MODE == M_FINAL) {
    Az = A + (long)(z >> 2) * 8388608 + (z & 3) * 1024;
    Bz = B + (long)(z >> 2) * 2097152 + (z & 3) * 1024;
  } else {
    Az = A + (long)z * sAz;
    Bz = B + (long)z * sBz;
  }

  const int srow = tid >> 2;
  const int scol = (((tid & 3) ^ ((tid >> 3) & 3)) << 3);
  const u16* aptr0 = Az + (long)(m0 + srow) * lda + scol;
  const u16* aptr1 = aptr0 + (long)64 * lda;
  const u16* bptr0 = Bz + (long)(n0 + srow) * ldb + scol;
  const u16* bptr1 = bptr0 + (long)64 * ldb;

  f32x4_t acc[4][4];
#pragma unroll
  for (int i = 0; i < 4; i++)
#pragma unroll
    for (int j = 0; j < 4; j++) acc[i][j] = (f32x4_t){0.f, 0.f, 0.f, 0.f};

  const int kg = lane >> 4;
  const int fr = lane & 15;
  const int nt = K >> 5;

  int aoffL[4], boffL[4];
#pragma unroll
  for (int i = 0; i < 4; i++) {
    const int r = wm + i * 16 + fr;
    aoffL[i] = r * 32 + ((kg ^ ((r >> 1) & 3)) << 3);
  }
#pragma unroll
  for (int j = 0; j < 4; j++) {
    const int r = wn + j * 16 + fr;
    boffL[j] = 4096 + r * 32 + ((kg ^ ((r >> 1) & 3)) << 3);
  }

  auto stage = [&](int t, u16* nb) {
    const int ko = t * 32;
    gload16(aptr0 + ko, nb + tid * 8);
    gload16(aptr1 + ko, nb + (tid + 256) * 8);
    gload16(bptr0 + ko, nb + 4096 + tid * 8);
    gload16(bptr1 + ko, nb + 4096 + (tid + 256) * 8);
  };

  stage(0, smem);
  stage(1, smem + 8192);

  for (int t = 0; t < nt; t++) {
    if (t < nt - 1) VMC(4);
    else            VMC(0);
    BAR();
    asm volatile("" ::: "memory");
    if (t + 2 < nt) stage(t + 2, smem + ((t + 2) % 3) * 8192);
    const u16* cb = smem + (t % 3) * 8192;
    bf16x8_t afr[4], bfr[4];
#pragma unroll
    for (int i = 0; i < 4; i++) afr[i] = *(const bf16x8_t*)&cb[aoffL[i]];
#pragma unroll
    for (int j = 0; j < 4; j++) bfr[j] = *(const bf16x8_t*)&cb[boffL[j]];
#pragma unroll
    for (int i = 0; i < 4; i++)
#pragma unroll
      for (int j = 0; j < 4; j++)
        acc[i][j] = __builtin_amdgcn_mfma_f32_16x16x32_bf16(afr[i], bfr[j], acc[i][j], 0, 0, 0);
  }
  __syncthreads();

  if constexpr (MODE == M_FINAL || MODE == M_CTXS) {
    float* o;
    if constexpr (MODE == M_FINAL)
      o = (float*)Cv + (long)(z & 3) * 4194304 + (long)(z >> 2) * 1048576;
    else
      o = (float*)Cv + (long)z * 262144;
#pragma unroll
    for (int i = 0; i < 4; i++) {
      const int rbase = m0 + wm + i * 16 + ((lane >> 4) << 2);
#pragma unroll
      for (int j = 0; j < 4; j++) {
        const int gc = n0 + wn + j * 16 + fr;
#pragma unroll
        for (int r = 0; r < 4; r++)
          o[(long)(rbase + r) * ldc + gc] = acc[i][j][r];
      }
    }
    return;
  }

  constexpr int CW = 136;
  u16* Cs = smem;
  if constexpr (MODE == M_W2) {
#pragma unroll
    for (int j = 0; j < 4; j++) {
      const int c = wn + j * 16 + fr;
#pragma unroll
      for (int i = 0; i < 4; i++) {
        us4 w;
#pragma unroll
        for (int r = 0; r < 4; r++) w.v[r] = f2bf(acc[i][j][r]);
        *(us4*)&Cs[c * CW + wm + i * 16 + ((lane >> 4) << 2)] = w;
      }
    }
  } else {
#pragma unroll
    for (int j = 0; j < 4; j++) {
      const int c = wn + j * 16 + fr;
#pragma unroll
      for (int i = 0; i < 4; i++) {
        const int rbase = wm + i * 16 + ((lane >> 4) << 2);
#pragma unroll
        for (int r = 0; r < 4; r++)
          Cs[(rbase + r) * CW + c] = f2bf(acc[i][j][r]);
      }
    }
  }
  __syncthreads();

  u16* dst = (u16*)Cv;
  if constexpr (MODE == M_W2) {
    const int b = z >> 3, h = z & 7;
    const long base0 = (long)b * 2097152 + (long)n0 * 4096 + ((m0 >> 4) << 7) + h * 16;
#pragma unroll
    for (int it = 0; it < 4; it++) {
      const int idx = it * 256 + tid;
      const int row = idx >> 3, ch = idx & 7;
      const long base = base0 + (long)row * 4096 + ch * 128;
      *(uint4*)&dst[base] = *(const uint4*)&Cs[row * CW + ch * 16];
      *(uint4*)&dst[base + 8] = *(const uint4*)&Cs[row * CW + ch * 16 + 8];
    }
  } else {  // M_PLAIN
    const long base = (long)z * sCz + (long)m0 * ldc + n0;
#pragma unroll
    for (int it = 0; it < 8; it++) {
      const int idx = it * 256 + tid;
      const int row = idx >> 4, ch = idx & 15;
      *(uint4*)&dst[base + (long)row * ldc + ch * 8] = *(const uint4*)&Cs[row * CW + ch * 8];
    }
  }
}

// ---------------- support kernels ----------------
__global__ void cvt3_kernel(const float* __restrict__ q, const float* __restrict__ k,
                            const float* __restrict__ v, u16* __restrict__ qb,
                            u16* __restrict__ kb, u16* __restrict__ vb) {
  const int arr = blockIdx.x >> 11;
  const int lb = blockIdx.x & 2047;
  const float* in = arr == 0 ? q : (arr == 1 ? k : v);
  u16* out = arr == 0 ? qb : (arr == 1 ? kb : vb);
  const long i = ((long)lb * 256 + threadIdx.x) * 8;
  float4 a = *(const float4*)(in + i);
  float4 b = *(const float4*)(in + i + 4);
  u16 t[8] = {f2bf(a.x), f2bf(a.y), f2bf(a.z), f2bf(a.w),
              f2bf(b.x), f2bf(b.y), f2bf(b.z), f2bf(b.w)};
  uint4 w; __builtin_memcpy(&w, t, 16);
  *(uint4*)(out + i) = w;
}

// WT[(e>>4)*128 + h*16 + (e&15)][d] = bf16(W[h][d][e])
__global__ void tcvt3_kernel(const float* __restrict__ Wq, const float* __restrict__ Wk,
                             const float* __restrict__ Wv, u16* __restrict__ WqT,
                             u16* __restrict__ WkT, u16* __restrict__ WvT)
{
  __shared__ float tile[32][33];
  const int arr = blockIdx.z >> 3;
  const int h = blockIdx.z & 7;
  const float* in = (arr == 0 ? Wq : (arr == 1 ? Wk : Wv)) + (long)h * 262144;
  u16* out = arr == 0 ? WqT : (arr == 1 ? WkT : WvT);
  const int c0 = blockIdx.x * 32, r0 = blockIdx.y * 32;
#pragma unroll
  for (int yy = threadIdx.y; yy < 32; yy += 8)
    tile[yy][threadIdx.x] = in[(long)(r0 + yy) * 512 + c0 + threadIdx.x];
  __syncthreads();
#pragma unroll
  for (int yy = threadIdx.y; yy < 32; yy += 8) {
    const int e = c0 + yy;
    const int rowp = ((e >> 4) << 7) + h * 16 + (e & 15);
    out[(long)rowp * 512 + r0 + threadIdx.x] = f2bf(tile[threadIdx.x][yy]);
  }
}

// WoT2[h][f][e] = bf16(Wo[e*8+h][f])
__global__ void tcvt_wo2(const float* __restrict__ in, u16* __restrict__ out) {
  __shared__ float tile[32][33];
  const int h = blockIdx.z;
  const int e0 = blockIdx.x * 32, f0 = blockIdx.y * 32;
#pragma unroll
  for (int yy = threadIdx.y; yy < 32; yy += 8)
    tile[yy][threadIdx.x] = in[(long)((e0 + yy) * 8 + h) * 512 + f0 + threadIdx.x];
  __syncthreads();
#pragma unroll
  for (int yy = threadIdx.y; yy < 32; yy += 8)
    out[(long)h * 262144 + (long)(f0 + yy) * 512 + e0 + threadIdx.x] =
        f2bf(tile[threadIdx.x][yy]);
}

__global__ void reduce4_kernel(const float* __restrict__ p, const float* __restrict__ bo,
                               float* __restrict__ out)
{
  const long S = 8192L * 512;
  const long i4 = ((long)blockIdx.x * 256 + threadIdx.x) * 4;
  float4 a = *(const float4*)(p + i4);
  float4 b = *(const float4*)(p + S + i4);
  float4 c = *(const float4*)(p + 2 * S + i4);
  float4 d = *(const float4*)(p + 3 * S + i4);
  float4 bb = *(const float4*)(bo + (i4 & 511));
  float4 r;
  r.x = a.x + b.x + c.x + d.x + bb.x;
  r.y = a.y + b.y + c.y + d.y + bb.y;
  r.z = a.z + b.z + c.z + d.z + bb.z;
  r.w = a.w + b.w + c.w + d.w + bb.w;
  *(float4*)(out + i4) = r;
}

__global__ void reduce2c_kernel(const float* __restrict__ p, u16* __restrict__ out)
{
  const long S = 32L * 262144;
  const long i = ((long)blockIdx.x * 256 + threadIdx.x) * 8;
  float4 a0 = *(const float4*)(p + i);
  float4 a1 = *(const float4*)(p + i + 4);
  float4 b0 = *(const float4*)(p + S + i);
  float4 b1 = *(const float4*)(p + S + i + 4);
  u16 t[8] = {f2bf(a0.x + b0.x), f2bf(a0.y + b0.y), f2bf(a0.z + b0.z), f2bf(a0.w + b0.w),
              f2bf(a1.x + b1.x), f2bf(a1.y + b1.y), f2bf(a1.z + b1.z), f2bf(a1.w + b1.w)};
  uint4 w; __builtin_memcpy(&w, t, 16);
  *(uint4*)(out + i) = w;
}

extern "C" void kernel_launch(void* const* d_in, const int* in_sizes, int n_in,
                              void* d_out, int out_size, void* d_ws, size_t ws_size,
                              hipStream_t stream) {
  const float* q  = (const float*)d_in[0];
  const float* k  = (const float*)d_in[1];
  const float* v  = (const float*)d_in[2];
  const float* Wq = (const float*)d_in[3];
  const float* bq = (const float*)d_in[4];
  const float* Wk = (const float*)d_in[5];
  const float* bk = (const float*)d_in[6];
  const float* Wv = (const float*)d_in[7];
  const float* bv = (const float*)d_in[8];
  const float* Wo = (const float*)d_in[9];
  const float* bo = (const float*)d_in[10];
  float* outp = (float*)d_out;

  char* ws = (char*)d_ws;
  // layout (peak 212 MiB), liveness verified per stage:
  u16* qs    = (u16*)(ws);                  //   0- 64 qsP; live to final
  u16* ksT   = (u16*)(ws + (64L  << 20));   //  64-128 [b,h,e,s]; dead after ctx
  u16* W2Pt  = (u16*)(ws + (64L  << 20));   //  64- 80 after ctx (ksT dead)
  u16* vsT   = (u16*)(ws + (128L << 20));   // 128-192 [b,h,e,s]; written launch B
  u16* qb    = (u16*)(ws + (128L << 20));   // 128-136 inside vsT; dead after launch A
  u16* kb    = (u16*)(ws + (136L << 20));   // 136-144 inside vsT; dead after launch A
  u16* WqT   = (u16*)(ws + (144L << 20));   // 144-148 inside vsT; dead after launch A
  u16* WkT   = (u16*)(ws + (148L << 20));   // 148-152 inside vsT; dead after launch A
  float* Pf  = (float*)(ws + (128L << 20)); // 128-192 final partials (vsT dead)
  u16* vb    = (u16*)(ws + (192L << 20));   // 192-200; dead after launch B
  u16* WvT   = (u16*)(ws + (200L << 20));   // 200-204; dead after launch B
  u16* ctxT  = (u16*)(ws + (192L << 20));   // 192-208 ctx (vb/WvT dead)
  u16* WoT2  = (u16*)(ws + (208L << 20));   // 208-212 [h][f][e]
  float* Pfc = (float*)(ws + (212L << 20)); // 212-276 ctx partials (guarded)
  const bool ctx_split = ws_size >= (286L << 20);

  cvt3_kernel<<<6144, 256, 0, stream>>>(q, k, v, qb, kb, vb);

  dim3 tb(32, 8, 1);
  tcvt3_kernel<<<dim3(16, 16, 24), tb, 0, stream>>>(Wq, Wk, Wv, WqT, WkT, WvT);
  tcvt_wo2<<<dim3(16, 16, 8), tb, 0, stream>>>(Wo, WoT2);

  // launch A: Q + K merged (zsel 0,1); launch B: V (zsel 2)
  proj3_kernel<<<4096, 256, 0, stream>>>(qb, kb, vb, WqT, WkT, WvT,
                                         bq, bk, bv, qs, ksT, vsT, 0);
  proj3_kernel<<<2048, 256, 0, stream>>>(qb, kb, vb, WqT, WkT, WvT,
                                         bq, bk, bv, qs, ksT, vsT, 2);

  // ctx[b,h][d][e] = sum_s ksT[d][s]*vsT[e][s]
  if (ctx_split) {
    gemm_kernel<M_CTXS><<<1024, 256, 0, stream>>>(
        ksT, 0, 2048, vsT, 0, 2048, Pfc, 0, 512, 4, 4, 1024);
    reduce2c_kernel<<<4096, 256, 0, stream>>>(Pfc, ctxT);
  } else {
    gemm_kernel<M_PLAIN><<<512, 256, 0, stream>>>(
        ksT, 1048576, 2048, vsT, 1048576, 2048, ctxT, 262144, 512, 4, 4, 2048);
  }

  // W2Pt[b][f][perm(h,d)] = sum_e ctx[b,h][d][e]*WoT2[h][f][e]
  gemm_kernel<M_W2><<<512, 256, 0, stream>>>(
      ctxT, 262144, 512, WoT2, 0, 512, W2Pt, 0, 0, 4, 4, 512);

  // final partials: K=4096 split 4x1024
  gemm_kernel<M_FINAL><<<1024, 256, 0, stream>>>(
      qs, 0, 4096, W2Pt, 0, 4096, Pf, 0, 512, 4, 16, 1024);

  reduce4_kernel<<<4096, 256, 0, stream>>>(Pf, bo, outp);
}

// Round 18
// 275.397 us; speedup vs baseline: 1.3040x; 1.0029x over previous
//
#include <hip/hip_runtime.h>
#include <hip/hip_bf16.h>

typedef unsigned short u16;
typedef __bf16 bf16x8_t __attribute__((ext_vector_type(8)));
typedef float f32x4_t __attribute__((ext_vector_type(4)));

struct alignas(8) us4 { u16 v[4]; };

__device__ __forceinline__ u16 f2bf(float f) {
  __hip_bfloat16 h = __float2bfloat16(f);
  u16 u; __builtin_memcpy(&u, &h, 2); return u;
}

__device__ __forceinline__ void gload16(const u16* g, u16* l) {
  __builtin_amdgcn_global_load_lds(
      (const __attribute__((address_space(1))) void*)g,
      (__attribute__((address_space(3))) void*)l, 16, 0, 0);
}

#define BAR()  __builtin_amdgcn_s_barrier()
#define VMC(n) asm volatile("s_waitcnt vmcnt(%0)" :: "i"(n) : "memory")

// ============ projection kernel (zsel picks q/k/v) ============
// big-ws path: ONE launch, grid 6144, zoff 0 -> zsel {0,1,2} (inputs live in
// dedicated non-aliased buffers). small-ws path: two launches (r17).
// 128x128 tile, BK=32, 3-buf depth-2 counted-vmcnt loop (48KB LDS -> 3
// blocks/CU), chunk-XOR swizzled LDS both-sides, 8x8 supertile block order
// (64 consecutive wg share 8 A-panels + 8 B-panels = 3MB -> L2-resident).
// Weights pre-interleaved (col n -> h=(n>>4)&7, e=(n>>7)*16+(n&15)).
// zsel 0: softmax + qsP[b][s][n]. zsel 1: softmax + [b,h,e,s].
// zsel 2: bias only + [b,h,e,s].
__global__ __launch_bounds__(256, 2)
void proj3_kernel(const u16* __restrict__ qb, const u16* __restrict__ kb,
                  const u16* __restrict__ vb, const u16* __restrict__ WqT,
                  const u16* __restrict__ WkT, const u16* __restrict__ WvT,
                  const float* __restrict__ bq, const float* __restrict__ bk,
                  const float* __restrict__ bv, u16* __restrict__ qs,
                  u16* __restrict__ ksT, u16* __restrict__ vsT, int zoff)
{
  __shared__ __align__(16) u16 smem[24576];

  const int bid = blockIdx.x;
  const int chunk = gridDim.x >> 3;
  const int wg = (bid & 7) * chunk + (bid >> 3);   // XCD-bijective (grid % 8 == 0)
  const int zsel = zoff + (wg >> 11);
  const int rem = wg & 2047;
  // supertile remap: st = 8 by-groups x 4 bx-groups; inner = 8x8 blocks
  const int st = rem >> 6;          // 0..31
  const int inner = rem & 63;       // 0..63
  const int by = ((st >> 2) << 3) + (inner >> 3);  // 0..63
  const int bx = ((st & 3) << 3) + (inner & 7);    // 0..31

  const int tid = threadIdx.x;
  const int lane = tid & 63;
  const int wave = tid >> 6;
  const int wm = (wave >> 1) * 64;
  const int wn = (wave & 1) * 64;
  const int m0 = by * 128;

  const u16* Az = zsel == 0 ? qb : (zsel == 1 ? kb : vb);
  const u16* Bz = zsel == 0 ? WqT : (zsel == 1 ? WkT : WvT);
  const float* bias = zsel == 0 ? bq : (zsel == 1 ? bk : bv);
  u16* outp = zsel == 0 ? qs : (zsel == 1 ? ksT : vsT);
  const bool doSM = (zsel < 2);

  const int srow = tid >> 2;
  const int scol = (((tid & 3) ^ ((tid >> 3) & 3)) << 3);
  const u16* aptr0 = Az + (long)(m0 + srow) * 512 + scol;
  const u16* aptr1 = aptr0 + (long)64 * 512;
  const u16* bptr0 = Bz + (long)(bx * 128 + srow) * 512 + scol;
  const u16* bptr1 = bptr0 + (long)64 * 512;

  f32x4_t acc[4][4];
#pragma unroll
  for (int i = 0; i < 4; i++)
#pragma unroll
    for (int j = 0; j < 4; j++) acc[i][j] = (f32x4_t){0.f, 0.f, 0.f, 0.f};

  const int kg = lane >> 4;
  const int fr = lane & 15;

  int aoffL[4], boffL[4];
#pragma unroll
  for (int i = 0; i < 4; i++) {
    const int r = wm + i * 16 + fr;
    aoffL[i] = r * 32 + ((kg ^ ((r >> 1) & 3)) << 3);
  }
#pragma unroll
  for (int j = 0; j < 4; j++) {
    const int r = wn + j * 16 + fr;
    boffL[j] = 4096 + r * 32 + ((kg ^ ((r >> 1) & 3)) << 3);
  }

  auto stage = [&](int t, u16* nb) {
    const int ko = t * 32;
    gload16(aptr0 + ko, nb + tid * 8);
    gload16(aptr1 + ko, nb + (tid + 256) * 8);
    gload16(bptr0 + ko, nb + 4096 + tid * 8);
    gload16(bptr1 + ko, nb + 4096 + (tid + 256) * 8);
  };

  stage(0, smem);
  stage(1, smem + 8192);

  for (int t = 0; t < 16; t++) {
    if (t < 15) VMC(4);
    else        VMC(0);
    BAR();
    asm volatile("" ::: "memory");
    if (t + 2 < 16) stage(t + 2, smem + ((t + 2) % 3) * 8192);
    const u16* cb = smem + (t % 3) * 8192;
    bf16x8_t afr[4], bfr[4];
#pragma unroll
    for (int i = 0; i < 4; i++) afr[i] = *(const bf16x8_t*)&cb[aoffL[i]];
#pragma unroll
    for (int j = 0; j < 4; j++) bfr[j] = *(const bf16x8_t*)&cb[boffL[j]];
#pragma unroll
    for (int i = 0; i < 4; i++)
#pragma unroll
      for (int j = 0; j < 4; j++)
        acc[i][j] = __builtin_amdgcn_mfma_f32_16x16x32_bf16(afr[i], bfr[j], acc[i][j], 0, 0, 0);
  }
  __syncthreads();  // full drain before smem reuse

  // ---- fused softmax over heads (zsel 0,1) ----
  if (doSM) {
    float* ex = (float*)smem;          // stride 17 -> conflict-free
    float* ex2 = ex + 4352;
    const int wmg = wave >> 1, wng = wave & 1;
    const int self = ((wmg * 2 + wng) * 64 + lane) * 17;
    const int part = ((wmg * 2 + (wng ^ 1)) * 64 + lane) * 17;
    float bj[4];
#pragma unroll
    for (int j = 0; j < 4; j++) bj[j] = bias[((wn >> 4) + j) * 512 + bx * 16 + fr];
#pragma unroll
    for (int i = 0; i < 4; i++)
#pragma unroll
      for (int j = 0; j < 4; j++)
#pragma unroll
        for (int r = 0; r < 4; r++) acc[i][j][r] += bj[j];
    float mx[16];
#pragma unroll
    for (int i = 0; i < 4; i++)
#pragma unroll
      for (int r = 0; r < 4; r++) {
        float m = acc[i][0][r];
#pragma unroll
        for (int j = 1; j < 4; j++) m = fmaxf(m, acc[i][j][r]);
        mx[i * 4 + r] = m;
      }
#pragma unroll
    for (int t = 0; t < 16; t++) ex[self + t] = mx[t];
    __syncthreads();
#pragma unroll
    for (int t = 0; t < 16; t++) mx[t] = fmaxf(mx[t], ex[part + t]);
    float sm[16];
#pragma unroll
    for (int t = 0; t < 16; t++) sm[t] = 0.f;
#pragma unroll
    for (int i = 0; i < 4; i++)
#pragma unroll
      for (int j = 0; j < 4; j++)
#pragma unroll
        for (int r = 0; r < 4; r++) {
          float p = __expf(acc[i][j][r] - mx[i * 4 + r]);
          acc[i][j][r] = p;
          sm[i * 4 + r] += p;
        }
#pragma unroll
    for (int t = 0; t < 16; t++) ex2[self + t] = sm[t];
    __syncthreads();
#pragma unroll
    for (int t = 0; t < 16; t++) sm[t] = 1.f / (sm[t] + ex2[part + t]);
#pragma unroll
    for (int i = 0; i < 4; i++)
#pragma unroll
      for (int j = 0; j < 4; j++)
#pragma unroll
        for (int r = 0; r < 4; r++) acc[i][j][r] *= sm[i * 4 + r];
    __syncthreads();
  }

  // ---- LDS-staged epilogue: Cs[128][136] ----
  constexpr int CW = 136;
  u16* Cs = smem;
  const int b = m0 >> 11, s0 = m0 & 2047;
  if (zsel == 0) {
    // qsP[b][s][bx*128 + c]
#pragma unroll
    for (int j = 0; j < 4; j++) {
      const int c = wn + j * 16 + fr;
#pragma unroll
      for (int i = 0; i < 4; i++) {
        const int rbase = wm + i * 16 + ((lane >> 4) << 2);
#pragma unroll
        for (int r = 0; r < 4; r++)
          Cs[(rbase + r) * CW + c] = f2bf(acc[i][j][r]);
      }
    }
    __syncthreads();
    const long base = (long)b * 8388608 + (long)s0 * 4096 + bx * 128;
#pragma unroll
    for (int it = 0; it < 8; it++) {
      const int idx = it * 256 + tid;
      const int row = idx >> 4, ch = idx & 15;
      *(uint4*)&outp[base + (long)row * 4096 + ch * 8] = *(const uint4*)&Cs[row * CW + ch * 8];
    }
  } else {
    // transposed tile: Cs[row = tile col c][col = s]; bias only for v (zsel 2)
#pragma unroll
    for (int j = 0; j < 4; j++) {
      const int c = wn + j * 16 + fr;
      const float bb = doSM ? 0.f : bias[((wn >> 4) + j) * 512 + bx * 16 + fr];
#pragma unroll
      for (int i = 0; i < 4; i++) {
        us4 w;
#pragma unroll
        for (int r = 0; r < 4; r++) w.v[r] = f2bf(acc[i][j][r] + bb);
        *(us4*)&Cs[c * CW + wm + i * 16 + ((lane >> 4) << 2)] = w;
      }
    }
    __syncthreads();
#pragma unroll
    for (int it = 0; it < 8; it++) {
      const int idx = it * 256 + tid;
      const int row = idx >> 4, ch = idx & 15;
      const long base = (long)(b * 8 + (row >> 4)) * 1048576 +
                        (long)(bx * 16 + (row & 15)) * 2048 + s0;
      *(uint4*)&outp[base + ch * 8] = *(const uint4*)&Cs[row * CW + ch * 8];
    }
  }
}

// ================= r9 128x128 core for ctx / W2 / final =================
#define M_PLAIN 2
#define M_W2    3
#define M_FINAL 4
#define M_CTXS  5

template<int MODE>
__global__ __launch_bounds__(256, 2)
void gemm_kernel(const u16* __restrict__ A, long sAz, int lda,
                 const u16* __restrict__ B, long sBz, int ldb,
                 void* __restrict__ Cv, long sCz, int ldc,
                 int nx, int ny, int K)
{
  __shared__ __align__(16) u16 smem[24576];

  const int nwg = gridDim.x;
  const int chunk = nwg >> 3;
  const int bid = blockIdx.x;
  const int wg = (bid & 7) * chunk + (bid >> 3);
  const int nxy = nx * ny;
  const int z = wg / nxy;
  const int rem = wg - z * nxy;
  const int by = rem / nx;
  const int bx = rem - by * nx;

  const int tid = threadIdx.x;
  const int lane = tid & 63;
  const int wave = tid >> 6;
  const int wm = (wave >> 1) * 64;
  const int wn = (wave & 1) * 64;
  const int m0 = by * 128;
  const int n0 = bx * 128;

  const u16* Az; const u16* Bz;
  if constexpr (MODE == M_CTXS) {
    const int bh = z & 31, kc = z >> 5;
    Az = A + (long)bh * 1048576 + kc * 1024;
    Bz = B + (long)bh * 1048576 + kc * 1024;
  } else if constexpr (MODE == M_W2) {
    Az = A + (long)z * 262144;
    Bz = B + (long)(z & 7) * 262144;
  } else if constexpr (MODE == M_FINAL) {
    Az = A + (long)(z >> 2) * 8388608 + (z & 3) * 1024;
    Bz = B + (long)(z >> 2) * 2097152 + (z & 3) * 1024;
  } else {
    Az = A + (long)z * sAz;
    Bz = B + (long)z * sBz;
  }

  const int srow = tid >> 2;
  const int scol = (((tid & 3) ^ ((tid >> 3) & 3)) << 3);
  const u16* aptr0 = Az + (long)(m0 + srow) * lda + scol;
  const u16* aptr1 = aptr0 + (long)64 * lda;
  const u16* bptr0 = Bz + (long)(n0 + srow) * ldb + scol;
  const u16* bptr1 = bptr0 + (long)64 * ldb;

  f32x4_t acc[4][4];
#pragma unroll
  for (int i = 0; i < 4; i++)
#pragma unroll
    for (int j = 0; j < 4; j++) acc[i][j] = (f32x4_t){0.f, 0.f, 0.f, 0.f};

  const int kg = lane >> 4;
  const int fr = lane & 15;
  const int nt = K >> 5;

  int aoffL[4], boffL[4];
#pragma unroll
  for (int i = 0; i < 4; i++) {
    const int r = wm + i * 16 + fr;
    aoffL[i] = r * 32 + ((kg ^ ((r >> 1) & 3)) << 3);
  }
#pragma unroll
  for (int j = 0; j < 4; j++) {
    const int r = wn + j * 16 + fr;
    boffL[j] = 4096 + r * 32 + ((kg ^ ((r >> 1) & 3)) << 3);
  }

  auto stage = [&](int t, u16* nb) {
    const int ko = t * 32;
    gload16(aptr0 + ko, nb + tid * 8);
    gload16(aptr1 + ko, nb + (tid + 256) * 8);
    gload16(bptr0 + ko, nb + 4096 + tid * 8);
    gload16(bptr1 + ko, nb + 4096 + (tid + 256) * 8);
  };

  stage(0, smem);
  stage(1, smem + 8192);

  for (int t = 0; t < nt; t++) {
    if (t < nt - 1) VMC(4);
    else            VMC(0);
    BAR();
    asm volatile("" ::: "memory");
    if (t + 2 < nt) stage(t + 2, smem + ((t + 2) % 3) * 8192);
    const u16* cb = smem + (t % 3) * 8192;
    bf16x8_t afr[4], bfr[4];
#pragma unroll
    for (int i = 0; i < 4; i++) afr[i] = *(const bf16x8_t*)&cb[aoffL[i]];
#pragma unroll
    for (int j = 0; j < 4; j++) bfr[j] = *(const bf16x8_t*)&cb[boffL[j]];
#pragma unroll
    for (int i = 0; i < 4; i++)
#pragma unroll
      for (int j = 0; j < 4; j++)
        acc[i][j] = __builtin_amdgcn_mfma_f32_16x16x32_bf16(afr[i], bfr[j], acc[i][j], 0, 0, 0);
  }
  __syncthreads();

  if constexpr (MODE == M_FINAL || MODE == M_CTXS) {
    float* o;
    if constexpr (MODE == M_FINAL)
      o = (float*)Cv + (long)(z & 3) * 4194304 + (long)(z >> 2) * 1048576;
    else
      o = (float*)Cv + (long)z * 262144;
#pragma unroll
    for (int i = 0; i < 4; i++) {
      const int rbase = m0 + wm + i * 16 + ((lane >> 4) << 2);
#pragma unroll
      for (int j = 0; j < 4; j++) {
        const int gc = n0 + wn + j * 16 + fr;
#pragma unroll
        for (int r = 0; r < 4; r++)
          o[(long)(rbase + r) * ldc + gc] = acc[i][j][r];
      }
    }
    return;
  }

  constexpr int CW = 136;
  u16* Cs = smem;
  if constexpr (MODE == M_W2) {
#pragma unroll
    for (int j = 0; j < 4; j++) {
      const int c = wn + j * 16 + fr;
#pragma unroll
      for (int i = 0; i < 4; i++) {
        us4 w;
#pragma unroll
        for (int r = 0; r < 4; r++) w.v[r] = f2bf(acc[i][j][r]);
        *(us4*)&Cs[c * CW + wm + i * 16 + ((lane >> 4) << 2)] = w;
      }
    }
  } else {
#pragma unroll
    for (int j = 0; j < 4; j++) {
      const int c = wn + j * 16 + fr;
#pragma unroll
      for (int i = 0; i < 4; i++) {
        const int rbase = wm + i * 16 + ((lane >> 4) << 2);
#pragma unroll
        for (int r = 0; r < 4; r++)
          Cs[(rbase + r) * CW + c] = f2bf(acc[i][j][r]);
      }
    }
  }
  __syncthreads();

  u16* dst = (u16*)Cv;
  if constexpr (MODE == M_W2) {
    const int b = z >> 3, h = z & 7;
    const long base0 = (long)b * 2097152 + (long)n0 * 4096 + ((m0 >> 4) << 7) + h * 16;
#pragma unroll
    for (int it = 0; it < 4; it++) {
      const int idx = it * 256 + tid;
      const int row = idx >> 3, ch = idx & 7;
      const long base = base0 + (long)row * 4096 + ch * 128;
      *(uint4*)&dst[base] = *(const uint4*)&Cs[row * CW + ch * 16];
      *(uint4*)&dst[base + 8] = *(const uint4*)&Cs[row * CW + ch * 16 + 8];
    }
  } else {  // M_PLAIN
    const long base = (long)z * sCz + (long)m0 * ldc + n0;
#pragma unroll
    for (int it = 0; it < 8; it++) {
      const int idx = it * 256 + tid;
      const int row = idx >> 4, ch = idx & 15;
      *(uint4*)&dst[base + (long)row * ldc + ch * 8] = *(const uint4*)&Cs[row * CW + ch * 8];
    }
  }
}

// ---------------- support kernels ----------------
__global__ void cvt3_kernel(const float* __restrict__ q, const float* __restrict__ k,
                            const float* __restrict__ v, u16* __restrict__ qb,
                            u16* __restrict__ kb, u16* __restrict__ vb) {
  const int arr = blockIdx.x >> 11;
  const int lb = blockIdx.x & 2047;
  const float* in = arr == 0 ? q : (arr == 1 ? k : v);
  u16* out = arr == 0 ? qb : (arr == 1 ? kb : vb);
  const long i = ((long)lb * 256 + threadIdx.x) * 8;
  float4 a = *(const float4*)(in + i);
  float4 b = *(const float4*)(in + i + 4);
  u16 t[8] = {f2bf(a.x), f2bf(a.y), f2bf(a.z), f2bf(a.w),
              f2bf(b.x), f2bf(b.y), f2bf(b.z), f2bf(b.w)};
  uint4 w; __builtin_memcpy(&w, t, 16);
  *(uint4*)(out + i) = w;
}

// WT[(e>>4)*128 + h*16 + (e&15)][d] = bf16(W[h][d][e])
__global__ void tcvt3_kernel(const float* __restrict__ Wq, const float* __restrict__ Wk,
                             const float* __restrict__ Wv, u16* __restrict__ WqT,
                             u16* __restrict__ WkT, u16* __restrict__ WvT)
{
  __shared__ float tile[32][33];
  const int arr = blockIdx.z >> 3;
  const int h = blockIdx.z & 7;
  const float* in = (arr == 0 ? Wq : (arr == 1 ? Wk : Wv)) + (long)h * 262144;
  u16* out = arr == 0 ? WqT : (arr == 1 ? WkT : WvT);
  const int c0 = blockIdx.x * 32, r0 = blockIdx.y * 32;
#pragma unroll
  for (int yy = threadIdx.y; yy < 32; yy += 8)
    tile[yy][threadIdx.x] = in[(long)(r0 + yy) * 512 + c0 + threadIdx.x];
  __syncthreads();
#pragma unroll
  for (int yy = threadIdx.y; yy < 32; yy += 8) {
    const int e = c0 + yy;
    const int rowp = ((e >> 4) << 7) + h * 16 + (e & 15);
    out[(long)rowp * 512 + r0 + threadIdx.x] = f2bf(tile[threadIdx.x][yy]);
  }
}

// WoT2[h][f][e] = bf16(Wo[e*8+h][f])
__global__ void tcvt_wo2(const float* __restrict__ in, u16* __restrict__ out) {
  __shared__ float tile[32][33];
  const int h = blockIdx.z;
  const int e0 = blockIdx.x * 32, f0 = blockIdx.y * 32;
#pragma unroll
  for (int yy = threadIdx.y; yy < 32; yy += 8)
    tile[yy][threadIdx.x] = in[(long)((e0 + yy) * 8 + h) * 512 + f0 + threadIdx.x];
  __syncthreads();
#pragma unroll
  for (int yy = threadIdx.y; yy < 32; yy += 8)
    out[(long)h * 262144 + (long)(f0 + yy) * 512 + e0 + threadIdx.x] =
        f2bf(tile[threadIdx.x][yy]);
}

__global__ void reduce4_kernel(const float* __restrict__ p, const float* __restrict__ bo,
                               float* __restrict__ out)
{
  const long S = 8192L * 512;
  const long i4 = ((long)blockIdx.x * 256 + threadIdx.x) * 4;
  float4 a = *(const float4*)(p + i4);
  float4 b = *(const float4*)(p + S + i4);
  float4 c = *(const float4*)(p + 2 * S + i4);
  float4 d = *(const float4*)(p + 3 * S + i4);
  float4 bb = *(const float4*)(bo + (i4 & 511));
  float4 r;
  r.x = a.x + b.x + c.x + d.x + bb.x;
  r.y = a.y + b.y + c.y + d.y + bb.y;
  r.z = a.z + b.z + c.z + d.z + bb.z;
  r.w = a.w + b.w + c.w + d.w + bb.w;
  *(float4*)(out + i4) = r;
}

__global__ void reduce2c_kernel(const float* __restrict__ p, u16* __restrict__ out)
{
  const long S = 32L * 262144;
  const long i = ((long)blockIdx.x * 256 + threadIdx.x) * 8;
  float4 a0 = *(const float4*)(p + i);
  float4 a1 = *(const float4*)(p + i + 4);
  float4 b0 = *(const float4*)(p + S + i);
  float4 b1 = *(const float4*)(p + S + i + 4);
  u16 t[8] = {f2bf(a0.x + b0.x), f2bf(a0.y + b0.y), f2bf(a0.z + b0.z), f2bf(a0.w + b0.w),
              f2bf(a1.x + b1.x), f2bf(a1.y + b1.y), f2bf(a1.z + b1.z), f2bf(a1.w + b1.w)};
  uint4 w; __builtin_memcpy(&w, t, 16);
  *(uint4*)(out + i) = w;
}

extern "C" void kernel_launch(void* const* d_in, const int* in_sizes, int n_in,
                              void* d_out, int out_size, void* d_ws, size_t ws_size,
                              hipStream_t stream) {
  const float* q  = (const float*)d_in[0];
  const float* k  = (const float*)d_in[1];
  const float* v  = (const float*)d_in[2];
  const float* Wq = (const float*)d_in[3];
  const float* bq = (const float*)d_in[4];
  const float* Wk = (const float*)d_in[5];
  const float* bk = (const float*)d_in[6];
  const float* Wv = (const float*)d_in[7];
  const float* bv = (const float*)d_in[8];
  const float* Wo = (const float*)d_in[9];
  const float* bo = (const float*)d_in[10];
  float* outp = (float*)d_out;

  char* ws = (char*)d_ws;
  const bool big = ws_size >= (286L << 20);

  // common outputs:
  u16* qs    = (u16*)(ws);                  //   0- 64 qsP; live to final
  u16* ksT   = (u16*)(ws + (64L  << 20));   //  64-128; dead after ctx
  u16* W2Pt  = (u16*)(ws + (64L  << 20));   //  64- 80 after ctx
  u16* vsT   = (u16*)(ws + (128L << 20));   // 128-192; dead after ctx
  float* Pf  = (float*)(ws + (128L << 20)); // 128-192 final partials (vsT dead)
  u16* ctxT  = (u16*)(ws + (192L << 20));   // 192-208
  u16* WoT2  = (u16*)(ws + (208L << 20));   // 208-212

  u16 *qb, *kb, *vb, *WqT, *WkT, *WvT;
  float* Pfc = (float*)(ws + (212L << 20)); // 212-276 ctx partials (big only)
  if (big) {
    // dedicated, never-overlapping input homes (dead before Pfc reuses 212-276)
    qb  = (u16*)(ws + (212L << 20));   // 212-220
    kb  = (u16*)(ws + (220L << 20));   // 220-228
    vb  = (u16*)(ws + (228L << 20));   // 228-236
    WqT = (u16*)(ws + (236L << 20));   // 236-240
    WkT = (u16*)(ws + (240L << 20));   // 240-244
    WvT = (u16*)(ws + (244L << 20));   // 244-248
  } else {
    // r17 time-aliased layout (launch-order contracts)
    qb  = (u16*)(ws + (128L << 20));   // inside vsT; dead after launch A
    kb  = (u16*)(ws + (136L << 20));
    WqT = (u16*)(ws + (144L << 20));
    WkT = (u16*)(ws + (148L << 20));
    vb  = (u16*)(ws + (192L << 20));   // dead after launch B (ctxT after)
    WvT = (u16*)(ws + (200L << 20));
  }

  cvt3_kernel<<<6144, 256, 0, stream>>>(q, k, v, qb, kb, vb);

  dim3 tb(32, 8, 1);
  tcvt3_kernel<<<dim3(16, 16, 24), tb, 0, stream>>>(Wq, Wk, Wv, WqT, WkT, WvT);
  tcvt_wo2<<<dim3(16, 16, 8), tb, 0, stream>>>(Wo, WoT2);

  if (big) {
    // single merged projection launch: zsel {0,1,2}, exactly 8 occupancy rounds
    proj3_kernel<<<6144, 256, 0, stream>>>(qb, kb, vb, WqT, WkT, WvT,
                                           bq, bk, bv, qs, ksT, vsT, 0);
  } else {
    proj3_kernel<<<4096, 256, 0, stream>>>(qb, kb, vb, WqT, WkT, WvT,
                                           bq, bk, bv, qs, ksT, vsT, 0);
    proj3_kernel<<<2048, 256, 0, stream>>>(qb, kb, vb, WqT, WkT, WvT,
                                           bq, bk, bv, qs, ksT, vsT, 2);
  }

  // ctx[b,h][d][e] = sum_s ksT[d][s]*vsT[e][s]
  if (big) {
    gemm_kernel<M_CTXS><<<1024, 256, 0, stream>>>(
        ksT, 0, 2048, vsT, 0, 2048, Pfc, 0, 512, 4, 4, 1024);
    reduce2c_kernel<<<4096, 256, 0, stream>>>(Pfc, ctxT);
  } else {
    gemm_kernel<M_PLAIN><<<512, 256, 0, stream>>>(
        ksT, 1048576, 2048, vsT, 1048576, 2048, ctxT, 262144, 512, 4, 4, 2048);
  }

  // W2Pt[b][f][perm(h,d)] = sum_e ctx[b,h][d][e]*WoT2[h][f][e]
  gemm_kernel<M_W2><<<512, 256, 0, stream>>>(
      ctxT, 262144, 512, WoT2, 0, 512, W2Pt, 0, 0, 4, 4, 512);

  // final partials: K=4096 split 4x1024
  gemm_kernel<M_FINAL><<<1024, 256, 0, stream>>>(
      qs, 0, 4096, W2Pt, 0, 4096, Pf, 0, 512, 4, 16, 1024);

  reduce4_kernel<<<4096, 256, 0, stream>>>(Pf, bo, outp);
}